// Round 8
// baseline (89.812 us; speedup 1.0000x reference)
//
#include <hip/hip_runtime.h>

#define B_ 8
#define S_ 2048
#define D_ 256

typedef _Float16 f16;
typedef f16 f16x2 __attribute__((ext_vector_type(2)));
typedef f16 f16x8 __attribute__((ext_vector_type(8)));
typedef float f32x16 __attribute__((ext_vector_type(16)));
typedef unsigned int u32;
typedef u32 u32x4 __attribute__((ext_vector_type(4)));

typedef const __attribute__((address_space(1))) unsigned int* gptr_t;
typedef __attribute__((address_space(3))) unsigned int* lptr_t;

__device__ __forceinline__ void gload_lds16(const void* g, void* l) {
  __builtin_amdgcn_global_load_lds((gptr_t)(unsigned long long)g,
                                   (lptr_t)(unsigned long long)l, 16, 0, 0);
}

__device__ __forceinline__ u32 packf16(float a, float b) {
  f16x2 t; t[0] = (f16)a; t[1] = (f16)b;
  return __builtin_bit_cast(u32, t);
}

__device__ __forceinline__ void barrier_raw() {
  __builtin_amdgcn_sched_barrier(0);
  __builtin_amdgcn_s_barrier();
  __builtin_amdgcn_sched_barrier(0);
}

// acc (lane-dim col, crow rows) -> lane holds its lane-row, crow-contiguous:
// s0 = crow 0..15 (16B at +hi*8), s1 = crow 16..31 (+16+hi*8).
__device__ __forceinline__ void pack16(const f32x16& p, int hi, u32x4& o0, u32x4& o1) {
#pragma unroll
  for (int c2 = 0; c2 < 2; ++c2) {
    u32 a1 = packf16(p[8 * c2 + 0], p[8 * c2 + 1]);
    u32 a2 = packf16(p[8 * c2 + 2], p[8 * c2 + 3]);
    u32 b1 = packf16(p[8 * c2 + 4], p[8 * c2 + 5]);
    u32 b2 = packf16(p[8 * c2 + 6], p[8 * c2 + 7]);
    u32 xa1 = __shfl_xor(a1, 32), xa2 = __shfl_xor(a2, 32);
    u32 xb1 = __shfl_xor(b1, 32), xb2 = __shfl_xor(b2, 32);
    u32x4 f;
    f[0] = hi ? xb1 : a1;
    f[1] = hi ? xb2 : a2;
    f[2] = hi ? b1 : xa1;
    f[3] = hi ? b2 : xa2;
    if (c2) o1 = f; else o0 = f;
  }
}

#define SC2F 0.09016844f   // log2(e)/16
#define NMAXR 20.0f        // >= max row norm (chi2_256 max ~ sqrt(397))
#define SWZ(r, s) ((s) ^ ((r) & 3) ^ (((r) >> 2) & 3))

// ---- fused prep: xh (f16), xt ([b][d][s]), n2 (row norms^2), Wt -----------
__global__ void prep(const float* __restrict__ x, const float* __restrict__ Wm,
                     const float* __restrict__ Wl, f16* __restrict__ xh,
                     f16* __restrict__ xt, float* __restrict__ n2,
                     f16* __restrict__ Wt) {
  __shared__ f16 tile[64][264];
  const int bid = blockIdx.x;
  const int t = threadIdx.x;          // 256
  if (bid < 256) {
    const int b = bid >> 5, st = bid & 31;
    const int s0 = st * 64;
    const float* xb = x + ((size_t)(b * S_ + s0)) * D_;
    f16* xhb = xh + ((size_t)(b * S_ + s0)) * D_;
#pragma unroll
    for (int it = 0; it < 16; ++it) {
      int flat = it * 256 + t;
      int r = flat >> 6, c4 = flat & 63;
      float4 v = *reinterpret_cast<const float4*>(xb + r * 256 + c4 * 4);
      f16 h0 = (f16)v.x, h1 = (f16)v.y, h2 = (f16)v.z, h3 = (f16)v.w;
      f16x2 p0 = {h0, h1}, p1 = {h2, h3};
      uint2 wv; wv.x = __builtin_bit_cast(u32, p0); wv.y = __builtin_bit_cast(u32, p1);
      *reinterpret_cast<uint2*>(xhb + r * 256 + c4 * 4) = wv;
      tile[r][c4 * 4 + 0] = h0; tile[r][c4 * 4 + 1] = h1;
      tile[r][c4 * 4 + 2] = h2; tile[r][c4 * 4 + 3] = h3;
    }
    __syncthreads();
    {
      int r = t >> 2, qd = t & 3;
      float s = 0.0f;
#pragma unroll
      for (int i = 0; i < 8; ++i) {
        f16x8 v = *reinterpret_cast<const f16x8*>(&tile[r][qd * 64 + i * 8]);
#pragma unroll
        for (int u = 0; u < 8; ++u) { float f = (float)v[u]; s += f * f; }
      }
      s += __shfl_xor(s, 1); s += __shfl_xor(s, 2);
      if (qd == 0) n2[b * S_ + s0 + r] = s;
    }
    {
      f16* xtb = xt + ((size_t)(b * D_ + t)) * S_ + s0;
#pragma unroll
      for (int s8 = 0; s8 < 8; ++s8) {
        f16x8 ov;
#pragma unroll
        for (int u = 0; u < 8; ++u) ov[u] = tile[s8 * 8 + u][t];
        *reinterpret_cast<f16x8*>(xtb + s8 * 8) = ov;
      }
    }
  } else {
    int idx = (bid - 256) * 1024 + t * 4;
    int j = idx >> 8, d = idx & 255;
#pragma unroll
    for (int k2 = 0; k2 < 4; ++k2) {
      float v = (j < 64) ? Wm[(d + k2) * 64 + j] : Wl[(d + k2) * 64 + (j - 64)];
      Wt[idx + k2] = (f16)v;
    }
  }
}

// ------ GEMM1: P[q][kv] = exp2(s*SC2 - R_q), Lp partials -------------------
// tile 128q x 256kv, K=256 in 8 steps of 32; grid bpp*128 (b fastest = XCD pin)
// 8 waves (wq2 x wk4): wave 64q x 64kv, acc[2][2], 1:1 mfma:ds_read
__launch_bounds__(512, 4)
__global__ void gemm1_kern(const f16* __restrict__ xh, const float* __restrict__ n2,
                           f16* __restrict__ P, float* __restrict__ Lp,
                           int b0, int bm, int bsh) {
  __shared__ f16 Aq[2][4096];   // [buf][128 q][32 d]
  __shared__ f16 Bk[2][8192];   // [buf][256 kv][32 d]
  const int idx = blockIdx.x;
  const int bl = idx & bm;
  const int kt = (idx >> bsh) & 7;
  const int qt = idx >> (bsh + 3);
  const int b = b0 + bl;
  const int qb = qt * 128, kb = kt * 256;
  const int tid = threadIdx.x, lane = tid & 63, w = tid >> 6;
  const int l31 = lane & 31, hi = lane >> 5;
  const int wq = w >> 2, wk = w & 3;
  const f16* xb = xh + (size_t)b * S_ * D_;

#define G1_STAGE(st, pp)                                                       \
  {                                                                            \
    { int c = tid; int r = c >> 2, sl = c & 3; int cs = SWZ(r, sl);            \
      gload_lds16(xb + (size_t)(qb + r) * 256 + (st) * 32 + cs * 8,            \
                  &Aq[pp][0] + c * 8); }                                       \
    _Pragma("unroll") for (int i = 0; i < 2; ++i) {                            \
      int c = i * 512 + tid; int r = c >> 2, sl = c & 3; int cs = SWZ(r, sl);  \
      gload_lds16(xb + (size_t)(kb + r) * 256 + (st) * 32 + cs * 8,            \
                  &Bk[pp][0] + c * 8); }                                       \
  }

#define G1_COMP(pp)                                                           \
  { _Pragma("unroll") for (int kc = 0; kc < 2; ++kc) {                        \
      int s = kc * 2 + hi;                                                    \
      f16x8 af[2], bf[2];                                                     \
      _Pragma("unroll") for (int mi = 0; mi < 2; ++mi) {                      \
        int row = wk * 64 + mi * 32 + l31;                                    \
        af[mi] = *reinterpret_cast<const f16x8*>(&Bk[pp][row * 32 + SWZ(row, s) * 8]); } \
      _Pragma("unroll") for (int ni = 0; ni < 2; ++ni) {                      \
        int row = wq * 64 + ni * 32 + l31;                                    \
        bf[ni] = *reinterpret_cast<const f16x8*>(&Aq[pp][row * 32 + SWZ(row, s) * 8]); } \
      _Pragma("unroll") for (int mi = 0; mi < 2; ++mi)                        \
        _Pragma("unroll") for (int ni = 0; ni < 2; ++ni)                      \
          acc[mi][ni] = __builtin_amdgcn_mfma_f32_32x32x16_f16(af[mi], bf[ni], acc[mi][ni], 0, 0, 0); \
    } }

  f32x16 acc[2][2];
#pragma unroll
  for (int i = 0; i < 2; ++i)
#pragma unroll
    for (int j = 0; j < 2; ++j)
#pragma unroll
      for (int e = 0; e < 16; ++e) acc[i][j][e] = 0.0f;

  G1_STAGE(0, 0);
  __syncthreads();
#pragma unroll 1
  for (int t = 0; t < 8; ++t) {
    const int p = t & 1;
    if (t < 7) G1_STAGE(t + 1, p ^ 1);
    G1_COMP(p);
    __syncthreads();
  }
#undef G1_STAGE
#undef G1_COMP

  // epilogue: exp2 with Cauchy-Schwarz shift; pack + store P; Lp partials
  float r2[2], lsum[2];
  int qrow[2];
#pragma unroll
  for (int ni = 0; ni < 2; ++ni) {
    qrow[ni] = qb + wq * 64 + ni * 32 + l31;
    r2[ni] = sqrtf(n2[b * S_ + qrow[ni]]) * (NMAXR * SC2F);
    lsum[ni] = 0.0f;
  }
#pragma unroll
  for (int mi = 0; mi < 2; ++mi)
#pragma unroll
    for (int ni = 0; ni < 2; ++ni)
#pragma unroll
      for (int j = 0; j < 16; ++j) {
        float v = exp2f(acc[mi][ni][j] * SC2F - r2[ni]);
        acc[mi][ni][j] = v;
        lsum[ni] += v;
      }
#pragma unroll
  for (int ni = 0; ni < 2; ++ni) lsum[ni] += __shfl_xor(lsum[ni], 32);

#pragma unroll
  for (int mi = 0; mi < 2; ++mi)
#pragma unroll
    for (int ni = 0; ni < 2; ++ni) {
      u32x4 s0, s1;
      pack16(acc[mi][ni], hi, s0, s1);
      size_t rowp = (size_t)(bl * S_ + qrow[ni]) * 2048;
      int colb = kb + wk * 64 + mi * 32;
      *reinterpret_cast<u32x4*>(P + rowp + colb + hi * 8) = s0;
      *reinterpret_cast<u32x4*>(P + rowp + colb + 16 + hi * 8) = s1;
    }

  float* Lred = (float*)(&Aq[0][0]);   // [128 q][4 wk]
  if (hi == 0) {
    Lred[(wq * 64 + l31) * 4 + wk] = lsum[0];
    Lred[(wq * 64 + 32 + l31) * 4 + wk] = lsum[1];
  }
  __syncthreads();
  if (tid < 128) {
    float s = Lred[tid * 4] + Lred[tid * 4 + 1] + Lred[tid * 4 + 2] + Lred[tid * 4 + 3];
    Lp[(size_t)(bl * 8 + kt) * 2048 + qb + tid] = s;
  }
}

// ------ GEMM2: A_det[q][d] = (P @ X)[q][d] / L[q] --------------------------
// tile 64q x 128d, K=2048 in 64 steps of 32; 4-deep bufs, counted vmcnt(6)
// 4 waves (wq2 x wd2): wave 32q x 64d acc[2]; grid bpp*64, 3 blocks/CU
__launch_bounds__(256, 3)
__global__ void gemm2_kern(const f16* __restrict__ P, const f16* __restrict__ xt,
                           const float* __restrict__ Lp, f16* __restrict__ adet,
                           int b0, int bm, int bsh) {
  __shared__ f16 Pt[4][2048];   // [buf][64 q][32 kv]
  __shared__ f16 Xt[4][4096];   // [buf][128 d][32 kv]
  const int idx = blockIdx.x;
  const int bl = idx & bm;
  const int dt = (idx >> bsh) & 1;
  const int qt = idx >> (bsh + 1);   // 0..31
  const int b = b0 + bl;
  const int qb = qt * 64, db = dt * 128;
  const int tid = threadIdx.x, lane = tid & 63, w = tid >> 6;
  const int l31 = lane & 31, hi = lane >> 5;
  const int wq = w & 1, wd = w >> 1;
  const f16* xtb = xt + (size_t)b * D_ * S_;

#define G2_STAGE(tt, tb)                                                       \
  {                                                                            \
    { int c = tid; int r = c >> 2, sl = c & 3; int cs = SWZ(r, sl);            \
      gload_lds16(P + (size_t)(bl * S_ + qb + r) * 2048 + (tt) * 32 + cs * 8,  \
                  &Pt[tb][0] + c * 8); }                                       \
    _Pragma("unroll") for (int i = 0; i < 2; ++i) {                            \
      int c = i * 256 + tid; int r = c >> 2, sl = c & 3; int cs = SWZ(r, sl);  \
      gload_lds16(xtb + (size_t)(db + r) * 2048 + (tt) * 32 + cs * 8,          \
                  &Xt[tb][0] + c * 8); }                                       \
  }

#define G2_COMP(tb)                                                           \
  { _Pragma("unroll") for (int kc = 0; kc < 2; ++kc) {                        \
      int s = kc * 2 + hi;                                                    \
      int qrow = wq * 32 + l31;                                               \
      f16x8 bf = *reinterpret_cast<const f16x8*>(&Pt[tb][qrow * 32 + SWZ(qrow, s) * 8]); \
      _Pragma("unroll") for (int ni = 0; ni < 2; ++ni) {                      \
        int drow = wd * 64 + ni * 32 + l31;                                   \
        f16x8 af = *reinterpret_cast<const f16x8*>(&Xt[tb][drow * 32 + SWZ(drow, s) * 8]); \
        acc[ni] = __builtin_amdgcn_mfma_f32_32x32x16_f16(af, bf, acc[ni], 0, 0, 0); \
      } } }

  f32x16 acc[2];
#pragma unroll
  for (int i = 0; i < 2; ++i)
#pragma unroll
    for (int e = 0; e < 16; ++e) acc[i][e] = 0.0f;

  G2_STAGE(0, 0);
  G2_STAGE(1, 1);
  G2_STAGE(2, 2);
#pragma unroll 1
  for (int t = 0; t < 62; ++t) {
    asm volatile("s_waitcnt vmcnt(6)" ::: "memory");
    barrier_raw();
    if (t < 61) G2_STAGE(t + 3, (t + 3) & 3);
    G2_COMP(t & 3);
  }
  asm volatile("s_waitcnt vmcnt(3)" ::: "memory");
  barrier_raw();
  G2_COMP(2);   // t = 62
  asm volatile("s_waitcnt vmcnt(0)" ::: "memory");
  barrier_raw();
  G2_COMP(3);   // t = 63
#undef G2_STAGE
#undef G2_COMP

  const int q = qb + wq * 32 + l31;
  float L = 0.0f;
#pragma unroll
  for (int kt = 0; kt < 8; ++kt) L += Lp[(size_t)(bl * 8 + kt) * 2048 + q];
  float rL = 1.0f / L;
#pragma unroll
  for (int ni = 0; ni < 2; ++ni)
#pragma unroll
    for (int e = 0; e < 16; ++e) acc[ni][e] *= rL;
#pragma unroll
  for (int ni = 0; ni < 2; ++ni) {
    u32x4 s0, s1;
    pack16(acc[ni], hi, s0, s1);
    f16* arow = adet + (size_t)(b * S_ + q) * 256 + db + wd * 64 + ni * 32;
    *reinterpret_cast<u32x4*>(arow + hi * 8) = s0;
    *reinterpret_cast<u32x4*>(arow + 16 + hi * 8) = s1;
  }
}

// ------- A_det @ [W_mean|W_logvar] + bias, reparam, write 3 outputs --------
__launch_bounds__(64)
__global__ void proj_kern(const f16* __restrict__ adet, const f16* __restrict__ Wt,
                          const float* __restrict__ bm, const float* __restrict__ bl,
                          const float* __restrict__ eps, float* __restrict__ out) {
  const int lane = threadIdx.x & 63;
  const int l31 = lane & 31, hi = lane >> 5;
  const int bidx = blockIdx.x;                       // 512; XCD-pin: b = bidx&7
  const int rb = ((bidx & 7) * 64 + (bidx >> 3)) * 32;
  f16x8 af[16];
  const f16* arow = adet + (size_t)(rb + l31) * 256;
#pragma unroll
  for (int kk = 0; kk < 16; ++kk)
    af[kk] = *reinterpret_cast<const f16x8*>(arow + kk * 16 + hi * 8);
  f32x16 acc[4];
#pragma unroll
  for (int i = 0; i < 4; ++i)
#pragma unroll
    for (int j = 0; j < 16; ++j) acc[i][j] = 0.0f;
#pragma unroll
  for (int ns = 0; ns < 4; ++ns) {
    const f16* wrow = Wt + (size_t)(l31 + 32 * ns) * 256;
#pragma unroll
    for (int kk = 0; kk < 16; ++kk) {
      f16x8 bf = *reinterpret_cast<const f16x8*>(wrow + kk * 16 + hi * 8);
      acc[ns] = __builtin_amdgcn_mfma_f32_32x32x16_f16(af[kk], bf, acc[ns], 0, 0, 0);
    }
  }
#pragma unroll
  for (int ns = 0; ns < 2; ++ns) {
    int c = l31 + 32 * ns;
    float bmv = bm[c], blv = bl[c];
#pragma unroll
    for (int r = 0; r < 16; ++r) {
      int row = (r & 3) + 8 * (r >> 2) + 4 * hi;
      int grow = rb + row;
      float mean = acc[ns][r] + bmv;
      float lv = acc[ns + 2][r] + blv;
      float e = eps[grow * 64 + c];
      float a = mean + exp2f(0.7213475204f * lv) * e;
      out[grow * 64 + c] = mean;
      out[1048576 + grow * 64 + c] = lv;
      out[2097152 + grow * 64 + c] = a;
    }
  }
}

extern "C" void kernel_launch(void* const* d_in, const int* in_sizes, int n_in,
                              void* d_out, int out_size, void* d_ws, size_t ws_size,
                              hipStream_t stream) {
  (void)in_sizes; (void)n_in; (void)out_size;
  const float* x   = (const float*)d_in[0];
  const float* Wm  = (const float*)d_in[1];
  const float* bmv = (const float*)d_in[2];
  const float* Wl  = (const float*)d_in[3];
  const float* blv = (const float*)d_in[4];
  const float* ep  = (const float*)d_in[5];
  float* out = (float*)d_out;

  char* ws = (char*)d_ws;
  f16*   xh   = (f16*)(ws + 0);              //  8 MB
  f16*   xt   = (f16*)(ws + 8388608);        //  8 MB
  f16*   adet = (f16*)(ws + 16777216);       //  8 MB
  f16*   Wt   = (f16*)(ws + 25165824);       // 64 KB
  float* n2   = (float*)(ws + 25231360);     // 64 KB
  float* Lp   = (float*)(ws + 25296896);     // <=512 KB
  const size_t P_off = 25821184;
  f16*   Pbuf = (f16*)(ws + P_off);

  int bpp = 1;
  if      (ws_size >= P_off + (size_t)8 * 2048 * 2048 * 2) bpp = 8;
  else if (ws_size >= P_off + (size_t)4 * 2048 * 2048 * 2) bpp = 4;
  else if (ws_size >= P_off + (size_t)2 * 2048 * 2048 * 2) bpp = 2;
  const int bsh = (bpp == 8) ? 3 : (bpp == 4) ? 2 : (bpp == 2) ? 1 : 0;
  const int bm = bpp - 1;

  prep<<<288, 256, 0, stream>>>(x, Wm, Wl, xh, xt, n2, Wt);
  for (int b0 = 0; b0 < 8; b0 += bpp) {
    gemm1_kern<<<bpp * 128, 512, 0, stream>>>(xh, n2, Pbuf, Lp, b0, bm, bsh);
    gemm2_kern<<<bpp * 64, 256, 0, stream>>>(Pbuf, xt, Lp, adet, b0, bm, bsh);
  }
  proj_kern<<<512, 64, 0, stream>>>(adet, Wt, bmv, blv, ep, out);
}

// Round 10
// 89.513 us; speedup vs baseline: 1.0033x; 1.0033x over previous
//
#include <hip/hip_runtime.h>

#define B_ 8
#define S_ 2048
#define D_ 256

typedef _Float16 f16;
typedef f16 f16x2 __attribute__((ext_vector_type(2)));
typedef f16 f16x8 __attribute__((ext_vector_type(8)));
typedef float f32x16 __attribute__((ext_vector_type(16)));
typedef unsigned int u32;
typedef u32 u32x4 __attribute__((ext_vector_type(4)));

typedef const __attribute__((address_space(1))) unsigned int* gptr_t;
typedef __attribute__((address_space(3))) unsigned int* lptr_t;

__device__ __forceinline__ void gload_lds16(const void* g, void* l) {
  __builtin_amdgcn_global_load_lds((gptr_t)(unsigned long long)g,
                                   (lptr_t)(unsigned long long)l, 16, 0, 0);
}

__device__ __forceinline__ u32 packf16(float a, float b) {
  f16x2 t; t[0] = (f16)a; t[1] = (f16)b;
  return __builtin_bit_cast(u32, t);
}

__device__ __forceinline__ void barrier_raw() {
  __builtin_amdgcn_sched_barrier(0);
  __builtin_amdgcn_s_barrier();
  __builtin_amdgcn_sched_barrier(0);
}

// acc (lane-dim col, crow rows) -> lane holds its lane-row, crow-contiguous:
// s0 = crow 0..15 (16B at +hi*8), s1 = crow 16..31 (+16+hi*8).
__device__ __forceinline__ void pack16(const f32x16& p, int hi, u32x4& o0, u32x4& o1) {
#pragma unroll
  for (int c2 = 0; c2 < 2; ++c2) {
    u32 a1 = packf16(p[8 * c2 + 0], p[8 * c2 + 1]);
    u32 a2 = packf16(p[8 * c2 + 2], p[8 * c2 + 3]);
    u32 b1 = packf16(p[8 * c2 + 4], p[8 * c2 + 5]);
    u32 b2 = packf16(p[8 * c2 + 6], p[8 * c2 + 7]);
    u32 xa1 = __shfl_xor(a1, 32), xa2 = __shfl_xor(a2, 32);
    u32 xb1 = __shfl_xor(b1, 32), xb2 = __shfl_xor(b2, 32);
    u32x4 f;
    f[0] = hi ? xb1 : a1;
    f[1] = hi ? xb2 : a2;
    f[2] = hi ? b1 : xa1;
    f[3] = hi ? b2 : xa2;
    if (c2) o1 = f; else o0 = f;
  }
}

#define SC2F 0.09016844f   // log2(e)/16
#define NMAXR 20.0f        // >= max row norm (chi2_256 max ~ sqrt(397))
#define SWZ(r, s) ((s) ^ ((r) & 3) ^ (((r) >> 2) & 3))

// ---- fused prep: xh (f16), xt ([b][d][s]), n2 (row norms^2), Wt -----------
__global__ void prep(const float* __restrict__ x, const float* __restrict__ Wm,
                     const float* __restrict__ Wl, f16* __restrict__ xh,
                     f16* __restrict__ xt, float* __restrict__ n2,
                     f16* __restrict__ Wt) {
  __shared__ f16 tile[64][264];
  const int bid = blockIdx.x;
  const int t = threadIdx.x;          // 256
  if (bid < 256) {
    const int b = bid >> 5, st = bid & 31;
    const int s0 = st * 64;
    const float* xb = x + ((size_t)(b * S_ + s0)) * D_;
    f16* xhb = xh + ((size_t)(b * S_ + s0)) * D_;
#pragma unroll
    for (int it = 0; it < 16; ++it) {
      int flat = it * 256 + t;
      int r = flat >> 6, c4 = flat & 63;
      float4 v = *reinterpret_cast<const float4*>(xb + r * 256 + c4 * 4);
      f16 h0 = (f16)v.x, h1 = (f16)v.y, h2 = (f16)v.z, h3 = (f16)v.w;
      f16x2 p0 = {h0, h1}, p1 = {h2, h3};
      uint2 wv; wv.x = __builtin_bit_cast(u32, p0); wv.y = __builtin_bit_cast(u32, p1);
      *reinterpret_cast<uint2*>(xhb + r * 256 + c4 * 4) = wv;
      tile[r][c4 * 4 + 0] = h0; tile[r][c4 * 4 + 1] = h1;
      tile[r][c4 * 4 + 2] = h2; tile[r][c4 * 4 + 3] = h3;
    }
    __syncthreads();
    {
      int r = t >> 2, qd = t & 3;
      float s = 0.0f;
#pragma unroll
      for (int i = 0; i < 8; ++i) {
        f16x8 v = *reinterpret_cast<const f16x8*>(&tile[r][qd * 64 + i * 8]);
#pragma unroll
        for (int u = 0; u < 8; ++u) { float f = (float)v[u]; s += f * f; }
      }
      s += __shfl_xor(s, 1); s += __shfl_xor(s, 2);
      if (qd == 0) n2[b * S_ + s0 + r] = s;
    }
    {
      f16* xtb = xt + ((size_t)(b * D_ + t)) * S_ + s0;
#pragma unroll
      for (int s8 = 0; s8 < 8; ++s8) {
        f16x8 ov;
#pragma unroll
        for (int u = 0; u < 8; ++u) ov[u] = tile[s8 * 8 + u][t];
        *reinterpret_cast<f16x8*>(xtb + s8 * 8) = ov;
      }
    }
  } else {
    int idx = (bid - 256) * 1024 + t * 4;
    int j = idx >> 8, d = idx & 255;
#pragma unroll
    for (int k2 = 0; k2 < 4; ++k2) {
      float v = (j < 64) ? Wm[(d + k2) * 64 + j] : Wl[(d + k2) * 64 + (j - 64)];
      Wt[idx + k2] = (f16)v;
    }
  }
}

// ------ GEMM1 (triangular): S-tile once, store P[q,kv] and P[kv,q] ---------
// tile 128q x 128kv, K=256 in 4 steps of 64; grid bpp*136 (b fastest = XCD pin)
// tiles enumerate kt >= qt; 8 waves (wq2 x wk4): wave 64q x 32kv, acc[2]
__launch_bounds__(512, 4)
__global__ void gemm1_kern(const f16* __restrict__ xh, const float* __restrict__ n2,
                           f16* __restrict__ P, int b0, int bm, int bsh) {
  __shared__ __align__(16) char smem[65536];
  f16* Aq = (f16*)smem;            // 2 bufs x [128 q][64 d]
  f16* Bk = (f16*)(smem + 32768);  // 2 bufs x [128 kv][64 d]
  const int idx = blockIdx.x;
  const int bl = idx & bm;
  int tdec = idx >> bsh;           // 0..135
  int qt = 0;
#pragma unroll 1
  while (tdec >= 16 - qt) { tdec -= 16 - qt; ++qt; }
  const int kt = qt + tdec;
  const int b = b0 + bl;
  const int qb = qt * 128, kb = kt * 128;
  const int tid = threadIdx.x, lane = tid & 63, w = tid >> 6;
  const int l31 = lane & 31, hi = lane >> 5;
  const int wq = w >> 2, wk = w & 3;
  const f16* xb = xh + (size_t)b * S_ * D_;

#define G1_STAGE(st, pp)                                                       \
  { _Pragma("unroll") for (int i = 0; i < 4; ++i) {                            \
      int ii = w * 4 + i;                                                      \
      int flat = ii * 64 + lane;                                               \
      bool isB = ii >= 16;                                                     \
      int ch = isB ? flat - 1024 : flat;                                       \
      int r = ch >> 3, c = ch & 7;                                             \
      int csrc = c ^ (r & 7);                                                  \
      const f16* src = xb + (size_t)((isB ? kb : qb) + r) * 256 +              \
                       (st) * 64 + csrc * 8;                                   \
      f16* dst = (isB ? Bk : Aq) + ((pp) * 8192) + ch * 8;                     \
      gload_lds16(src, dst);                                                   \
    } }

  f32x16 acc[2];
#pragma unroll
  for (int i = 0; i < 2; ++i)
#pragma unroll
    for (int e = 0; e < 16; ++e) acc[i][e] = 0.0f;

  G1_STAGE(0, 0);
  __syncthreads();
#pragma unroll
  for (int t = 0; t < 4; ++t) {
    const int p = t & 1;
    if (t < 3) G1_STAGE(t + 1, p ^ 1);
#pragma unroll
    for (int kc = 0; kc < 4; ++kc) {
      int cc = ((2 * kc + hi) ^ (l31 & 7)) * 8;
      f16x8 af  = *reinterpret_cast<const f16x8*>(Bk + p * 8192 + (wk * 32 + l31) * 64 + cc);
      f16x8 bf0 = *reinterpret_cast<const f16x8*>(Aq + p * 8192 + (wq * 64 + l31) * 64 + cc);
      f16x8 bf1 = *reinterpret_cast<const f16x8*>(Aq + p * 8192 + (wq * 64 + 32 + l31) * 64 + cc);
      acc[0] = __builtin_amdgcn_mfma_f32_32x32x16_f16(af, bf0, acc[0], 0, 0, 0);
      acc[1] = __builtin_amdgcn_mfma_f32_32x32x16_f16(af, bf1, acc[1], 0, 0, 0);
    }
    __syncthreads();
  }
#undef G1_STAGE

  // ---- raw S into LDS (f32, XOR-swizzled cols) for the transposed store ----
  float* raw = (float*)smem;   // [128 kv][128 q]
  if (kt != qt) {
#pragma unroll
    for (int ni = 0; ni < 2; ++ni)
#pragma unroll
      for (int j = 0; j < 16; ++j) {
        int kvloc = wk * 32 + (j & 3) + 8 * (j >> 2) + 4 * hi;
        int qloc = wq * 64 + ni * 32 + l31;
        raw[kvloc * 128 + (qloc ^ ((kvloc & 7) << 2))] = acc[ni][j];
      }
  }

  // ---- normal epilogue (register path): P[q][kv], shift R_q ----
  float r2[2];
  int qrow[2];
#pragma unroll
  for (int ni = 0; ni < 2; ++ni) {
    qrow[ni] = qb + wq * 64 + ni * 32 + l31;
    r2[ni] = sqrtf(n2[b * S_ + qrow[ni]]) * (NMAXR * SC2F);
  }
#pragma unroll
  for (int ni = 0; ni < 2; ++ni)
#pragma unroll
    for (int j = 0; j < 16; ++j)
      acc[ni][j] = exp2f(acc[ni][j] * SC2F - r2[ni]);

  const int colb = kb + wk * 32;
#pragma unroll
  for (int ni = 0; ni < 2; ++ni) {
    u32x4 s0, s1;
    pack16(acc[ni], hi, s0, s1);
    size_t rowp = (size_t)(bl * S_ + qrow[ni]) * 2048;
    *reinterpret_cast<u32x4*>(P + rowp + colb + hi * 8) = s0;
    *reinterpret_cast<u32x4*>(P + rowp + colb + 16 + hi * 8) = s1;
  }

  // ---- transposed epilogue: P[kv][q], shift R_kv ----
  if (kt != qt) {
    __syncthreads();
    const int kvr = tid >> 2;
    const int qseg = (tid & 3) * 32;
    float r2kv = sqrtf(n2[b * S_ + kb + kvr]) * (NMAXR * SC2F);
    u32 ow[16];
#pragma unroll
    for (int c8 = 0; c8 < 8; ++c8) {
      int qs = qseg + c8 * 4;
      float4 v = *reinterpret_cast<const float4*>(
          &raw[kvr * 128 + (qs ^ ((kvr & 7) << 2))]);
      ow[c8 * 2 + 0] = packf16(exp2f(v.x * SC2F - r2kv), exp2f(v.y * SC2F - r2kv));
      ow[c8 * 2 + 1] = packf16(exp2f(v.z * SC2F - r2kv), exp2f(v.w * SC2F - r2kv));
    }
    size_t rowp = (size_t)(bl * S_ + kb + kvr) * 2048;
#pragma unroll
    for (int sseg = 0; sseg < 4; ++sseg) {
      u32x4 sv;
      sv[0] = ow[sseg * 4 + 0]; sv[1] = ow[sseg * 4 + 1];
      sv[2] = ow[sseg * 4 + 2]; sv[3] = ow[sseg * 4 + 3];
      *reinterpret_cast<u32x4*>(P + rowp + qb + qseg + sseg * 8) = sv;
    }
  }
}

// ------ GEMM2: A_det[q][d] = (P @ X)[q][d] / L[q], L summed in-loop --------
// tile 64q x 128d, K=2048 in 64 steps of 32; 4-deep bufs, counted vmcnt(6)
// 4 waves (wq2 x wd2): wave 32q x 64d acc[2]; grid bpp*64, 3 blocks/CU
__launch_bounds__(256, 3)
__global__ void gemm2_kern(const f16* __restrict__ P, const f16* __restrict__ xt,
                           f16* __restrict__ adet, int b0, int bm, int bsh) {
  __shared__ f16 Pt[4][2048];   // [buf][64 q][32 kv]
  __shared__ f16 Xt[4][4096];   // [buf][128 d][32 kv]
  const int idx = blockIdx.x;
  const int bl = idx & bm;
  const int dt = (idx >> bsh) & 1;
  const int qt = idx >> (bsh + 1);   // 0..31
  const int b = b0 + bl;
  const int qb = qt * 64, db = dt * 128;
  const int tid = threadIdx.x, lane = tid & 63, w = tid >> 6;
  const int l31 = lane & 31, hi = lane >> 5;
  const int wq = w & 1, wd = w >> 1;
  const f16* xtb = xt + (size_t)b * D_ * S_;

#define G2_STAGE(tt, tb)                                                       \
  {                                                                            \
    { int c = tid; int r = c >> 2, sl = c & 3; int cs = SWZ(r, sl);            \
      gload_lds16(P + (size_t)(bl * S_ + qb + r) * 2048 + ((tt) * 32) + cs * 8,\
                  &Pt[(tb)][0] + c * 8); }                                     \
    _Pragma("unroll") for (int i = 0; i < 2; ++i) {                            \
      int c = i * 256 + tid; int r = c >> 2, sl = c & 3; int cs = SWZ(r, sl);  \
      gload_lds16(xtb + (size_t)(db + r) * 2048 + ((tt) * 32) + cs * 8,        \
                  &Xt[(tb)][0] + c * 8); }                                     \
  }

#define G2_COMP(tb)                                                           \
  { _Pragma("unroll") for (int kc = 0; kc < 2; ++kc) {                        \
      int s = kc * 2 + hi;                                                    \
      int qrow = wq * 32 + l31;                                               \
      f16x8 bf = *reinterpret_cast<const f16x8*>(&Pt[(tb)][qrow * 32 + SWZ(qrow, s) * 8]); \
      { const f16x2* pp2 = reinterpret_cast<const f16x2*>(&bf);               \
        f16x2 sa = pp2[0] + pp2[1];                                           \
        f16x2 sb = pp2[2] + pp2[3];                                           \
        sa = sa + sb;                                                         \
        lsum += (float)sa[0] + (float)sa[1]; }                                \
      _Pragma("unroll") for (int ni = 0; ni < 2; ++ni) {                      \
        int drow = wd * 64 + ni * 32 + l31;                                   \
        f16x8 af = *reinterpret_cast<const f16x8*>(&Xt[(tb)][drow * 32 + SWZ(drow, s) * 8]); \
        acc[ni] = __builtin_amdgcn_mfma_f32_32x32x16_f16(af, bf, acc[ni], 0, 0, 0); \
      } } }

  f32x16 acc[2];
#pragma unroll
  for (int i = 0; i < 2; ++i)
#pragma unroll
    for (int e = 0; e < 16; ++e) acc[i][e] = 0.0f;
  float lsum = 0.0f;

  G2_STAGE(0, 0);
  G2_STAGE(1, 1);
  G2_STAGE(2, 2);
#pragma unroll 1
  for (int t = 0; t < 62; ++t) {
    asm volatile("s_waitcnt vmcnt(6)" ::: "memory");
    barrier_raw();
    if (t < 61) G2_STAGE(t + 3, (t + 3) & 3);
    G2_COMP(t & 3);
  }
  asm volatile("s_waitcnt vmcnt(3)" ::: "memory");
  barrier_raw();
  G2_COMP(2);   // t = 62
  asm volatile("s_waitcnt vmcnt(0)" ::: "memory");
  barrier_raw();
  G2_COMP(3);   // t = 63
#undef G2_STAGE
#undef G2_COMP

  const int q = qb + wq * 32 + l31;
  float L = lsum + __shfl_xor(lsum, 32);
  float rL = 1.0f / L;
#pragma unroll
  for (int ni = 0; ni < 2; ++ni)
#pragma unroll
    for (int e = 0; e < 16; ++e) acc[ni][e] *= rL;
#pragma unroll
  for (int ni = 0; ni < 2; ++ni) {
    u32x4 s0, s1;
    pack16(acc[ni], hi, s0, s1);
    f16* arow = adet + (size_t)(b * S_ + q) * 256 + db + wd * 64 + ni * 32;
    *reinterpret_cast<u32x4*>(arow + hi * 8) = s0;
    *reinterpret_cast<u32x4*>(arow + 16 + hi * 8) = s1;
  }
}

// ------- A_det @ [W_mean|W_logvar] + bias, reparam, write 3 outputs --------
__launch_bounds__(64)
__global__ void proj_kern(const f16* __restrict__ adet, const f16* __restrict__ Wt,
                          const float* __restrict__ bm, const float* __restrict__ bl,
                          const float* __restrict__ eps, float* __restrict__ out) {
  const int lane = threadIdx.x & 63;
  const int l31 = lane & 31, hi = lane >> 5;
  const int bidx = blockIdx.x;                       // 512; XCD-pin: b = bidx&7
  const int rb = ((bidx & 7) * 64 + (bidx >> 3)) * 32;
  f16x8 af[16];
  const f16* arow = adet + (size_t)(rb + l31) * 256;
#pragma unroll
  for (int kk = 0; kk < 16; ++kk)
    af[kk] = *reinterpret_cast<const f16x8*>(arow + kk * 16 + hi * 8);
  f32x16 acc[4];
#pragma unroll
  for (int i = 0; i < 4; ++i)
#pragma unroll
    for (int j = 0; j < 16; ++j) acc[i][j] = 0.0f;
#pragma unroll
  for (int ns = 0; ns < 4; ++ns) {
    const f16* wrow = Wt + (size_t)(l31 + 32 * ns) * 256;
#pragma unroll
    for (int kk = 0; kk < 16; ++kk) {
      f16x8 bf = *reinterpret_cast<const f16x8*>(wrow + kk * 16 + hi * 8);
      acc[ns] = __builtin_amdgcn_mfma_f32_32x32x16_f16(af[kk], bf, acc[ns], 0, 0, 0);
    }
  }
#pragma unroll
  for (int ns = 0; ns < 2; ++ns) {
    int c = l31 + 32 * ns;
    float bmv = bm[c], blv = bl[c];
#pragma unroll
    for (int r = 0; r < 16; ++r) {
      int row = (r & 3) + 8 * (r >> 2) + 4 * hi;
      int grow = rb + row;
      float mean = acc[ns][r] + bmv;
      float lv = acc[ns + 2][r] + blv;
      float e = eps[grow * 64 + c];
      float a = mean + exp2f(0.7213475204f * lv) * e;
      out[grow * 64 + c] = mean;
      out[1048576 + grow * 64 + c] = lv;
      out[2097152 + grow * 64 + c] = a;
    }
  }
}

extern "C" void kernel_launch(void* const* d_in, const int* in_sizes, int n_in,
                              void* d_out, int out_size, void* d_ws, size_t ws_size,
                              hipStream_t stream) {
  (void)in_sizes; (void)n_in; (void)out_size;
  const float* x   = (const float*)d_in[0];
  const float* Wm  = (const float*)d_in[1];
  const float* bmv = (const float*)d_in[2];
  const float* Wl  = (const float*)d_in[3];
  const float* blv = (const float*)d_in[4];
  const float* ep  = (const float*)d_in[5];
  float* out = (float*)d_out;

  char* ws = (char*)d_ws;
  f16*   xh   = (f16*)(ws + 0);              //  8 MB
  f16*   xt   = (f16*)(ws + 8388608);        //  8 MB
  f16*   adet = (f16*)(ws + 16777216);       //  8 MB
  f16*   Wt   = (f16*)(ws + 25165824);       // 64 KB
  float* n2   = (float*)(ws + 25231360);     // 64 KB
  const size_t P_off = 25821184;
  f16*   Pbuf = (f16*)(ws + P_off);

  int bpp = 1;
  if      (ws_size >= P_off + (size_t)8 * 2048 * 2048 * 2) bpp = 8;
  else if (ws_size >= P_off + (size_t)4 * 2048 * 2048 * 2) bpp = 4;
  else if (ws_size >= P_off + (size_t)2 * 2048 * 2048 * 2) bpp = 2;
  const int bsh = (bpp == 8) ? 3 : (bpp == 4) ? 2 : (bpp == 2) ? 1 : 0;
  const int bm = bpp - 1;

  prep<<<288, 256, 0, stream>>>(x, Wm, Wl, xh, xt, n2, Wt);
  for (int b0 = 0; b0 < 8; b0 += bpp) {
    gemm1_kern<<<bpp * 136, 512, 0, stream>>>(xh, n2, Pbuf, b0, bm, bsh);
    gemm2_kern<<<bpp * 64, 256, 0, stream>>>(Pbuf, xt, adet, b0, bm, bsh);
  }
  proj_kern<<<512, 64, 0, stream>>>(adet, Wt, bmv, blv, ep, out);
}

// Round 11
// 83.547 us; speedup vs baseline: 1.0750x; 1.0714x over previous
//
#include <hip/hip_runtime.h>

#define B_ 8
#define S_ 2048
#define D_ 256

typedef _Float16 f16;
typedef f16 f16x2 __attribute__((ext_vector_type(2)));
typedef f16 f16x8 __attribute__((ext_vector_type(8)));
typedef float f32x16 __attribute__((ext_vector_type(16)));
typedef unsigned int u32;
typedef u32 u32x4 __attribute__((ext_vector_type(4)));

typedef const __attribute__((address_space(1))) unsigned int* gptr_t;
typedef __attribute__((address_space(3))) unsigned int* lptr_t;

__device__ __forceinline__ void gload_lds16(const void* g, void* l) {
  __builtin_amdgcn_global_load_lds((gptr_t)(unsigned long long)g,
                                   (lptr_t)(unsigned long long)l, 16, 0, 0);
}

__device__ __forceinline__ u32 packf16(float a, float b) {
  f16x2 t; t[0] = (f16)a; t[1] = (f16)b;
  return __builtin_bit_cast(u32, t);
}

// acc (lane-dim col, crow rows) -> lane holds its lane-row, crow-contiguous:
// s0 = crow 0..15 (16B at +hi*8), s1 = crow 16..31 (+16+hi*8).
__device__ __forceinline__ void pack16(const f32x16& p, int hi, u32x4& o0, u32x4& o1) {
#pragma unroll
  for (int c2 = 0; c2 < 2; ++c2) {
    u32 a1 = packf16(p[8 * c2 + 0], p[8 * c2 + 1]);
    u32 a2 = packf16(p[8 * c2 + 2], p[8 * c2 + 3]);
    u32 b1 = packf16(p[8 * c2 + 4], p[8 * c2 + 5]);
    u32 b2 = packf16(p[8 * c2 + 6], p[8 * c2 + 7]);
    u32 xa1 = __shfl_xor(a1, 32), xa2 = __shfl_xor(a2, 32);
    u32 xb1 = __shfl_xor(b1, 32), xb2 = __shfl_xor(b2, 32);
    u32x4 f;
    f[0] = hi ? xb1 : a1;
    f[1] = hi ? xb2 : a2;
    f[2] = hi ? b1 : xa1;
    f[3] = hi ? b2 : xa2;
    if (c2) o1 = f; else o0 = f;
  }
}

#define SC2F 0.09016844f   // log2(e)/16
#define NMAXR 20.0f        // >= max row norm (chi2_256 max ~ sqrt(397))
#define SWZ(r, s) ((s) ^ ((r) & 3) ^ (((r) >> 2) & 3))

// ---- fused prep: xh (f16), xt ([b][d][s]), n2 (row norms^2), Wt -----------
__global__ void prep(const float* __restrict__ x, const float* __restrict__ Wm,
                     const float* __restrict__ Wl, f16* __restrict__ xh,
                     f16* __restrict__ xt, float* __restrict__ n2,
                     f16* __restrict__ Wt) {
  __shared__ f16 tile[64][264];
  const int bid = blockIdx.x;
  const int t = threadIdx.x;          // 256
  if (bid < 256) {
    const int b = bid >> 5, st = bid & 31;
    const int s0 = st * 64;
    const float* xb = x + ((size_t)(b * S_ + s0)) * D_;
    f16* xhb = xh + ((size_t)(b * S_ + s0)) * D_;
#pragma unroll
    for (int it = 0; it < 16; ++it) {
      int flat = it * 256 + t;
      int r = flat >> 6, c4 = flat & 63;
      float4 v = *reinterpret_cast<const float4*>(xb + r * 256 + c4 * 4);
      f16 h0 = (f16)v.x, h1 = (f16)v.y, h2 = (f16)v.z, h3 = (f16)v.w;
      f16x2 p0 = {h0, h1}, p1 = {h2, h3};
      uint2 wv; wv.x = __builtin_bit_cast(u32, p0); wv.y = __builtin_bit_cast(u32, p1);
      *reinterpret_cast<uint2*>(xhb + r * 256 + c4 * 4) = wv;
      tile[r][c4 * 4 + 0] = h0; tile[r][c4 * 4 + 1] = h1;
      tile[r][c4 * 4 + 2] = h2; tile[r][c4 * 4 + 3] = h3;
    }
    __syncthreads();
    {
      int r = t >> 2, qd = t & 3;
      float s = 0.0f;
#pragma unroll
      for (int i = 0; i < 8; ++i) {
        f16x8 v = *reinterpret_cast<const f16x8*>(&tile[r][qd * 64 + i * 8]);
#pragma unroll
        for (int u = 0; u < 8; ++u) { float f = (float)v[u]; s += f * f; }
      }
      s += __shfl_xor(s, 1); s += __shfl_xor(s, 2);
      if (qd == 0) n2[b * S_ + s0 + r] = s;
    }
    {
      f16* xtb = xt + ((size_t)(b * D_ + t)) * S_ + s0;
#pragma unroll
      for (int s8 = 0; s8 < 8; ++s8) {
        f16x8 ov;
#pragma unroll
        for (int u = 0; u < 8; ++u) ov[u] = tile[s8 * 8 + u][t];
        *reinterpret_cast<f16x8*>(xtb + s8 * 8) = ov;
      }
    }
  } else {
    int idx = (bid - 256) * 1024 + t * 4;
    int j = idx >> 8, d = idx & 255;
#pragma unroll
    for (int k2 = 0; k2 < 4; ++k2) {
      float v = (j < 64) ? Wm[(d + k2) * 64 + j] : Wl[(d + k2) * 64 + (j - 64)];
      Wt[idx + k2] = (f16)v;
    }
  }
}

// ------ GEMM1 (triangular): S-tile once, store P[q,kv] and P[kv,q], Lp -----
// tile 128q x 128kv, K=256 in 4 steps of 64; grid bpp*136 (b fastest = XCD pin)
// tiles enumerate kt >= qt; 8 waves (wq2 x wk4): wave 64q x 32kv, acc[2]
__launch_bounds__(512, 4)
__global__ void gemm1_kern(const f16* __restrict__ xh, const float* __restrict__ n2,
                           f16* __restrict__ P, float* __restrict__ Lp,
                           int b0, int bm, int bsh) {
  __shared__ __align__(16) char smem[65536];
  f16* Aq = (f16*)smem;            // 2 bufs x [128 q][64 d]
  f16* Bk = (f16*)(smem + 32768);  // 2 bufs x [128 kv][64 d]
  const int idx = blockIdx.x;
  const int bl = idx & bm;
  int tdec = idx >> bsh;           // 0..135
  int qt = 0;
#pragma unroll 1
  while (tdec >= 16 - qt) { tdec -= 16 - qt; ++qt; }
  const int kt = qt + tdec;
  const int b = b0 + bl;
  const int qb = qt * 128, kb = kt * 128;
  const int tid = threadIdx.x, lane = tid & 63, w = tid >> 6;
  const int l31 = lane & 31, hi = lane >> 5;
  const int wq = w >> 2, wk = w & 3;
  const f16* xb = xh + (size_t)b * S_ * D_;

#define G1_STAGE(st, pp)                                                       \
  { _Pragma("unroll") for (int i = 0; i < 4; ++i) {                            \
      int ii = w * 4 + i;                                                      \
      int flat = ii * 64 + lane;                                               \
      bool isB = ii >= 16;                                                     \
      int ch = isB ? flat - 1024 : flat;                                       \
      int r = ch >> 3, c = ch & 7;                                             \
      int csrc = c ^ (r & 7);                                                  \
      const f16* src = xb + (size_t)((isB ? kb : qb) + r) * 256 +              \
                       (st) * 64 + csrc * 8;                                   \
      f16* dst = (isB ? Bk : Aq) + ((pp) * 8192) + ch * 8;                     \
      gload_lds16(src, dst);                                                   \
    } }

  f32x16 acc[2];
#pragma unroll
  for (int i = 0; i < 2; ++i)
#pragma unroll
    for (int e = 0; e < 16; ++e) acc[i][e] = 0.0f;

  G1_STAGE(0, 0);
  __syncthreads();
#pragma unroll
  for (int t = 0; t < 4; ++t) {
    const int p = t & 1;
    if (t < 3) G1_STAGE(t + 1, p ^ 1);
#pragma unroll
    for (int kc = 0; kc < 4; ++kc) {
      int cc = ((2 * kc + hi) ^ (l31 & 7)) * 8;
      f16x8 af  = *reinterpret_cast<const f16x8*>(Bk + p * 8192 + (wk * 32 + l31) * 64 + cc);
      f16x8 bf0 = *reinterpret_cast<const f16x8*>(Aq + p * 8192 + (wq * 64 + l31) * 64 + cc);
      f16x8 bf1 = *reinterpret_cast<const f16x8*>(Aq + p * 8192 + (wq * 64 + 32 + l31) * 64 + cc);
      acc[0] = __builtin_amdgcn_mfma_f32_32x32x16_f16(af, bf0, acc[0], 0, 0, 0);
      acc[1] = __builtin_amdgcn_mfma_f32_32x32x16_f16(af, bf1, acc[1], 0, 0, 0);
    }
    __syncthreads();
  }
#undef G1_STAGE

  // ---- raw S into LDS (f32, XOR-swizzled cols) for the transposed store ----
  float* raw = (float*)smem;   // [128 kv][128 q]
  if (kt != qt) {
#pragma unroll
    for (int ni = 0; ni < 2; ++ni)
#pragma unroll
      for (int j = 0; j < 16; ++j) {
        int kvloc = wk * 32 + (j & 3) + 8 * (j >> 2) + 4 * hi;
        int qloc = wq * 64 + ni * 32 + l31;
        raw[kvloc * 128 + (qloc ^ ((kvloc & 7) << 2))] = acc[ni][j];
      }
  }

  // ---- register epilogue: P[q][kv], shift R_q, row-sum partials ----
  float r2[2], lsum[2];
  int qrow[2];
#pragma unroll
  for (int ni = 0; ni < 2; ++ni) {
    qrow[ni] = qb + wq * 64 + ni * 32 + l31;
    r2[ni] = sqrtf(n2[b * S_ + qrow[ni]]) * (NMAXR * SC2F);
    lsum[ni] = 0.0f;
  }
#pragma unroll
  for (int ni = 0; ni < 2; ++ni)
#pragma unroll
    for (int j = 0; j < 16; ++j) {
      float v = exp2f(acc[ni][j] * SC2F - r2[ni]);
      acc[ni][j] = v;
      lsum[ni] += v;
    }
#pragma unroll
  for (int ni = 0; ni < 2; ++ni) lsum[ni] += __shfl_xor(lsum[ni], 32);

  const int colb = kb + wk * 32;
#pragma unroll
  for (int ni = 0; ni < 2; ++ni) {
    u32x4 s0, s1;
    pack16(acc[ni], hi, s0, s1);
    size_t rowp = (size_t)(bl * S_ + qrow[ni]) * 2048;
    *reinterpret_cast<u32x4*>(P + rowp + colb + hi * 8) = s0;
    *reinterpret_cast<u32x4*>(P + rowp + colb + 16 + hi * 8) = s1;
  }

  // ---- transposed epilogue: P[kv][q], shift R_kv, col-sum partials ----
  if (kt != qt) {
    __syncthreads();
    const int kvr = tid >> 2;
    const int qseg = (tid & 3) * 32;
    float r2kv = sqrtf(n2[b * S_ + kb + kvr]) * (NMAXR * SC2F);
    u32 ow[16];
    float tsum = 0.0f;
#pragma unroll
    for (int c8 = 0; c8 < 8; ++c8) {
      int qs = qseg + c8 * 4;
      float4 v = *reinterpret_cast<const float4*>(
          &raw[kvr * 128 + (qs ^ ((kvr & 7) << 2))]);
      float e0 = exp2f(v.x * SC2F - r2kv), e1 = exp2f(v.y * SC2F - r2kv);
      float e2 = exp2f(v.z * SC2F - r2kv), e3 = exp2f(v.w * SC2F - r2kv);
      tsum += (e0 + e1) + (e2 + e3);
      ow[c8 * 2 + 0] = packf16(e0, e1);
      ow[c8 * 2 + 1] = packf16(e2, e3);
    }
    size_t rowp = (size_t)(bl * S_ + kb + kvr) * 2048;
#pragma unroll
    for (int sseg = 0; sseg < 4; ++sseg) {
      u32x4 sv;
      sv[0] = ow[sseg * 4 + 0]; sv[1] = ow[sseg * 4 + 1];
      sv[2] = ow[sseg * 4 + 2]; sv[3] = ow[sseg * 4 + 3];
      *reinterpret_cast<u32x4*>(P + rowp + qb + qseg + sseg * 8) = sv;
    }
    tsum += __shfl_xor(tsum, 1);
    tsum += __shfl_xor(tsum, 2);
    if ((tid & 3) == 0)
      Lp[(size_t)(bl * 16 + qt) * 2048 + kb + kvr] = tsum;
  }

  // ---- Lred reduce for register-path partials (smem free after this sync) --
  __syncthreads();
  float* Lred = (float*)smem;   // [128 q][4 wk]
  if (hi == 0) {
    Lred[(wq * 64 + l31) * 4 + wk] = lsum[0];
    Lred[(wq * 64 + 32 + l31) * 4 + wk] = lsum[1];
  }
  __syncthreads();
  if (tid < 128) {
    float s = Lred[tid * 4] + Lred[tid * 4 + 1] + Lred[tid * 4 + 2] + Lred[tid * 4 + 3];
    Lp[(size_t)(bl * 16 + kt) * 2048 + qb + tid] = s;
  }
}

// ------ GEMM2: A_det[q][d] = (P @ X)[q][d] / L[q] (R7 structure) -----------
// tile 128q x 64d, K=2048 in 32 steps of 64; grid bpp*64:
//   bl = idx & (bpp-1) (XCD pin), dt = next 2 bits, qt = top
__launch_bounds__(512, 6)
__global__ void gemm2_kern(const f16* __restrict__ P, const f16* __restrict__ xt,
                           const float* __restrict__ Lp, f16* __restrict__ adet,
                           int b0, int bm, int bsh) {
  __shared__ f16 Pt[2][8192];   // [buf][128 q][64 kv]
  __shared__ f16 Xt[2][4096];   // [buf][64 d][64 kv]
  const int idx = blockIdx.x;
  const int bl = idx & bm;
  const int dt = (idx >> bsh) & 3;
  const int qt = idx >> (bsh + 2);
  const int b = b0 + bl;
  const int qb = qt * 128, db = dt * 64;
  const int tid = threadIdx.x, lane = tid & 63, w = tid >> 6;
  const int l31 = lane & 31, hi = lane >> 5;
  const int wq = w >> 1, wd = w & 1;
  const f16* xtb = xt + (size_t)b * D_ * S_;

#define G2_STAGE(st, pp)                                                       \
  { _Pragma("unroll") for (int i = 0; i < 3; ++i) {                            \
      int ii = w * 3 + i;                                                      \
      int flat = ii * 64 + lane;                                               \
      bool isX = ii >= 16;                                                     \
      int ch = isX ? flat - 1024 : flat;                                       \
      int r = ch >> 3, c = ch & 7;                                             \
      int csrc = c ^ (r & 7);                                                  \
      const f16* src = isX                                                     \
          ? xtb + (size_t)(db + r) * 2048 + ((st) * 64) + csrc * 8             \
          : P + (size_t)(bl * S_ + qb + r) * 2048 + ((st) * 64) + csrc * 8;    \
      f16* dst = (isX ? &Xt[(pp)][0] : &Pt[(pp)][0]) + ch * 8;                 \
      gload_lds16(src, dst);                                                   \
    } }

  f32x16 acc;
#pragma unroll
  for (int e = 0; e < 16; ++e) acc[e] = 0.0f;

  G2_STAGE(0, 0);
  __syncthreads();
#pragma unroll 1
  for (int t = 0; t < 32; ++t) {
    const int p = t & 1;
    if (t < 31) G2_STAGE(t + 1, p ^ 1);
#pragma unroll
    for (int kc = 0; kc < 4; ++kc) {
      int cc = ((2 * kc + hi) ^ (l31 & 7)) * 8;
      f16x8 af = *reinterpret_cast<const f16x8*>(&Xt[p][(wd * 32 + l31) * 64 + cc]);
      f16x8 bf = *reinterpret_cast<const f16x8*>(&Pt[p][(wq * 32 + l31) * 64 + cc]);
      acc = __builtin_amdgcn_mfma_f32_32x32x16_f16(af, bf, acc, 0, 0, 0);
    }
    __syncthreads();
  }
#undef G2_STAGE

  const int q = qb + wq * 32 + l31;
  float L = 0.0f;
#pragma unroll
  for (int kt = 0; kt < 16; ++kt) L += Lp[(size_t)(bl * 16 + kt) * 2048 + q];
  float rL = 1.0f / L;
#pragma unroll
  for (int e = 0; e < 16; ++e) acc[e] *= rL;
  u32x4 s0, s1;
  pack16(acc, hi, s0, s1);
  f16* arow = adet + (size_t)(b * S_ + q) * 256 + db + wd * 32;
  *reinterpret_cast<u32x4*>(arow + hi * 8) = s0;
  *reinterpret_cast<u32x4*>(arow + 16 + hi * 8) = s1;
}

// ------- A_det @ [W_mean|W_logvar] + bias, reparam, write 3 outputs --------
__launch_bounds__(64)
__global__ void proj_kern(const f16* __restrict__ adet, const f16* __restrict__ Wt,
                          const float* __restrict__ bm, const float* __restrict__ bl,
                          const float* __restrict__ eps, float* __restrict__ out) {
  const int lane = threadIdx.x & 63;
  const int l31 = lane & 31, hi = lane >> 5;
  const int bidx = blockIdx.x;                       // 512; XCD-pin: b = bidx&7
  const int rb = ((bidx & 7) * 64 + (bidx >> 3)) * 32;
  f16x8 af[16];
  const f16* arow = adet + (size_t)(rb + l31) * 256;
#pragma unroll
  for (int kk = 0; kk < 16; ++kk)
    af[kk] = *reinterpret_cast<const f16x8*>(arow + kk * 16 + hi * 8);
  f32x16 acc[4];
#pragma unroll
  for (int i = 0; i < 4; ++i)
#pragma unroll
    for (int j = 0; j < 16; ++j) acc[i][j] = 0.0f;
#pragma unroll
  for (int ns = 0; ns < 4; ++ns) {
    const f16* wrow = Wt + (size_t)(l31 + 32 * ns) * 256;
#pragma unroll
    for (int kk = 0; kk < 16; ++kk) {
      f16x8 bf = *reinterpret_cast<const f16x8*>(wrow + kk * 16 + hi * 8);
      acc[ns] = __builtin_amdgcn_mfma_f32_32x32x16_f16(af[kk], bf, acc[ns], 0, 0, 0);
    }
  }
#pragma unroll
  for (int ns = 0; ns < 2; ++ns) {
    int c = l31 + 32 * ns;
    float bmv = bm[c], blv = bl[c];
#pragma unroll
    for (int r = 0; r < 16; ++r) {
      int row = (r & 3) + 8 * (r >> 2) + 4 * hi;
      int grow = rb + row;
      float mean = acc[ns][r] + bmv;
      float lv = acc[ns + 2][r] + blv;
      float e = eps[grow * 64 + c];
      float a = mean + exp2f(0.7213475204f * lv) * e;
      out[grow * 64 + c] = mean;
      out[1048576 + grow * 64 + c] = lv;
      out[2097152 + grow * 64 + c] = a;
    }
  }
}

extern "C" void kernel_launch(void* const* d_in, const int* in_sizes, int n_in,
                              void* d_out, int out_size, void* d_ws, size_t ws_size,
                              hipStream_t stream) {
  (void)in_sizes; (void)n_in; (void)out_size;
  const float* x   = (const float*)d_in[0];
  const float* Wm  = (const float*)d_in[1];
  const float* bmv = (const float*)d_in[2];
  const float* Wl  = (const float*)d_in[3];
  const float* blv = (const float*)d_in[4];
  const float* ep  = (const float*)d_in[5];
  float* out = (float*)d_out;

  char* ws = (char*)d_ws;
  f16*   xh   = (f16*)(ws + 0);              //  8 MB
  f16*   xt   = (f16*)(ws + 8388608);        //  8 MB
  f16*   adet = (f16*)(ws + 16777216);       //  8 MB
  f16*   Wt   = (f16*)(ws + 25165824);       // 64 KB
  float* n2   = (float*)(ws + 25231360);     // 64 KB
  float* Lp   = (float*)(ws + 25296896);     // <=1 MB
  const size_t P_off = 26345472;
  f16*   Pbuf = (f16*)(ws + P_off);

  int bpp = 1;
  if      (ws_size >= P_off + (size_t)8 * 2048 * 2048 * 2) bpp = 8;
  else if (ws_size >= P_off + (size_t)4 * 2048 * 2048 * 2) bpp = 4;
  else if (ws_size >= P_off + (size_t)2 * 2048 * 2048 * 2) bpp = 2;
  const int bsh = (bpp == 8) ? 3 : (bpp == 4) ? 2 : (bpp == 2) ? 1 : 0;
  const int bm = bpp - 1;

  prep<<<288, 256, 0, stream>>>(x, Wm, Wl, xh, xt, n2, Wt);
  for (int b0 = 0; b0 < 8; b0 += bpp) {
    gemm1_kern<<<bpp * 136, 512, 0, stream>>>(xh, n2, Pbuf, Lp, b0, bm, bsh);
    gemm2_kern<<<bpp * 64, 512, 0, stream>>>(Pbuf, xt, Lp, adet, b0, bm, bsh);
  }
  proj_kern<<<512, 64, 0, stream>>>(adet, Wt, bmv, blv, ep, out);
}

// Round 12
// 75.901 us; speedup vs baseline: 1.1833x; 1.1007x over previous
//
#include <hip/hip_runtime.h>

#define B_ 8
#define S_ 2048
#define D_ 256

typedef _Float16 f16;
typedef f16 f16x2 __attribute__((ext_vector_type(2)));
typedef f16 f16x8 __attribute__((ext_vector_type(8)));
typedef float f32x16 __attribute__((ext_vector_type(16)));
typedef unsigned int u32;
typedef u32 u32x4 __attribute__((ext_vector_type(4)));

typedef const __attribute__((address_space(1))) unsigned int* gptr_t;
typedef __attribute__((address_space(3))) unsigned int* lptr_t;

__device__ __forceinline__ void gload_lds16(const void* g, void* l) {
  __builtin_amdgcn_global_load_lds((gptr_t)(unsigned long long)g,
                                   (lptr_t)(unsigned long long)l, 16, 0, 0);
}

__device__ __forceinline__ u32 packf16(float a, float b) {
  f16x2 t; t[0] = (f16)a; t[1] = (f16)b;
  return __builtin_bit_cast(u32, t);
}

// acc (lane-dim col, crow rows) -> lane holds its lane-row, crow-contiguous:
// s0 = crow 0..15 (16B at +hi*8), s1 = crow 16..31 (+16+hi*8).
__device__ __forceinline__ void pack16(const f32x16& p, int hi, u32x4& o0, u32x4& o1) {
#pragma unroll
  for (int c2 = 0; c2 < 2; ++c2) {
    u32 a1 = packf16(p[8 * c2 + 0], p[8 * c2 + 1]);
    u32 a2 = packf16(p[8 * c2 + 2], p[8 * c2 + 3]);
    u32 b1 = packf16(p[8 * c2 + 4], p[8 * c2 + 5]);
    u32 b2 = packf16(p[8 * c2 + 6], p[8 * c2 + 7]);
    u32 xa1 = __shfl_xor(a1, 32), xa2 = __shfl_xor(a2, 32);
    u32 xb1 = __shfl_xor(b1, 32), xb2 = __shfl_xor(b2, 32);
    u32x4 f;
    f[0] = hi ? xb1 : a1;
    f[1] = hi ? xb2 : a2;
    f[2] = hi ? b1 : xa1;
    f[3] = hi ? b2 : xa2;
    if (c2) o1 = f; else o0 = f;
  }
}

#define SC2F 0.09016844f   // log2(e)/16
#define NMAXR 20.0f        // >= max row norm (chi2_256 max ~ sqrt(397))

// ---- fused prep: xh (f16), n2 (row norms^2), Wt[128 j][256 d] -------------
__global__ void prep(const float* __restrict__ x, const float* __restrict__ Wm,
                     const float* __restrict__ Wl, f16* __restrict__ xh,
                     float* __restrict__ n2, f16* __restrict__ Wt) {
  __shared__ f16 tile[64][264];
  const int bid = blockIdx.x;
  const int t = threadIdx.x;          // 256
  if (bid < 256) {
    const int b = bid >> 5, st = bid & 31;
    const int s0 = st * 64;
    const float* xb = x + ((size_t)(b * S_ + s0)) * D_;
    f16* xhb = xh + ((size_t)(b * S_ + s0)) * D_;
#pragma unroll
    for (int it = 0; it < 16; ++it) {
      int flat = it * 256 + t;
      int r = flat >> 6, c4 = flat & 63;
      float4 v = *reinterpret_cast<const float4*>(xb + r * 256 + c4 * 4);
      f16 h0 = (f16)v.x, h1 = (f16)v.y, h2 = (f16)v.z, h3 = (f16)v.w;
      f16x2 p0 = {h0, h1}, p1 = {h2, h3};
      uint2 wv; wv.x = __builtin_bit_cast(u32, p0); wv.y = __builtin_bit_cast(u32, p1);
      *reinterpret_cast<uint2*>(xhb + r * 256 + c4 * 4) = wv;
      tile[r][c4 * 4 + 0] = h0; tile[r][c4 * 4 + 1] = h1;
      tile[r][c4 * 4 + 2] = h2; tile[r][c4 * 4 + 3] = h3;
    }
    __syncthreads();
    {
      int r = t >> 2, qd = t & 3;
      float s = 0.0f;
#pragma unroll
      for (int i = 0; i < 8; ++i) {
        f16x8 v = *reinterpret_cast<const f16x8*>(&tile[r][qd * 64 + i * 8]);
#pragma unroll
        for (int u = 0; u < 8; ++u) { float f = (float)v[u]; s += f * f; }
      }
      s += __shfl_xor(s, 1); s += __shfl_xor(s, 2);
      if (qd == 0) n2[b * S_ + s0 + r] = s;
    }
  } else {
    int idx = (bid - 256) * 1024 + t * 4;
    int j = idx >> 8, d = idx & 255;
#pragma unroll
    for (int k2 = 0; k2 < 4; ++k2) {
      float v = (j < 64) ? Wm[(d + k2) * 64 + j] : Wl[(d + k2) * 64 + (j - 64)];
      Wt[idx + k2] = (f16)v;
    }
  }
}

// ---- xw: XWt[b][j 128][s 2048] = (xh @ Wt^T)^T, f16 -----------------------
// grid 256: b = idx&7 (XCD pin), sbt = idx>>3 (64 s rows); 4 waves (wj4)
// mfma(af = xh s-rows -> crow = s, bf = Wt j-rows -> lane = j)
__launch_bounds__(256)
__global__ void xw_kern(const f16* __restrict__ xh, const f16* __restrict__ Wt,
                        f16* __restrict__ XWt) {
  __shared__ f16 Ax[2][4096];   // [buf][64 s][64 d]
  __shared__ f16 Ww[2][8192];   // [buf][128 j][64 d]
  const int idx = blockIdx.x;
  const int b = idx & 7;
  const int sb = (idx >> 3) * 64;
  const int tid = threadIdx.x, lane = tid & 63, w = tid >> 6;   // w = wj
  const int l31 = lane & 31, hi = lane >> 5;
  const f16* xb = xh + (size_t)b * S_ * D_;

#define XW_STAGE(st, pp)                                                       \
  {                                                                            \
    _Pragma("unroll") for (int i = 0; i < 2; ++i) {                            \
      int ch = i * 256 + tid; int r = ch >> 3, c = ch & 7;                     \
      int csrc = c ^ (r & 7);                                                  \
      gload_lds16(xb + (size_t)(sb + r) * 256 + ((st) * 64) + csrc * 8,        \
                  &Ax[(pp)][0] + ch * 8);                                      \
    }                                                                          \
    _Pragma("unroll") for (int i = 0; i < 4; ++i) {                            \
      int ch = i * 256 + tid; int r = ch >> 3, c = ch & 7;                     \
      int csrc = c ^ (r & 7);                                                  \
      gload_lds16(Wt + (size_t)r * 256 + ((st) * 64) + csrc * 8,               \
                  &Ww[(pp)][0] + ch * 8);                                      \
    }                                                                          \
  }

  f32x16 acc[2];
#pragma unroll
  for (int i = 0; i < 2; ++i)
#pragma unroll
    for (int e = 0; e < 16; ++e) acc[i][e] = 0.0f;

  XW_STAGE(0, 0);
  __syncthreads();
#pragma unroll
  for (int t = 0; t < 4; ++t) {
    const int p = t & 1;
    if (t < 3) XW_STAGE(t + 1, p ^ 1);
#pragma unroll
    for (int kc = 0; kc < 4; ++kc) {
      int cc = ((2 * kc + hi) ^ (l31 & 7)) * 8;
      f16x8 bf = *reinterpret_cast<const f16x8*>(&Ww[p][(w * 32 + l31) * 64 + cc]);
#pragma unroll
      for (int mi = 0; mi < 2; ++mi) {
        f16x8 af = *reinterpret_cast<const f16x8*>(&Ax[p][(mi * 32 + l31) * 64 + cc]);
        acc[mi] = __builtin_amdgcn_mfma_f32_32x32x16_f16(af, bf, acc[mi], 0, 0, 0);
      }
    }
    __syncthreads();
  }
#undef XW_STAGE

  const int j = w * 32 + l31;
  f16* dst = XWt + ((size_t)b * 128 + j) * 2048;
#pragma unroll
  for (int mi = 0; mi < 2; ++mi) {
    u32x4 s0, s1;
    pack16(acc[mi], hi, s0, s1);
    *reinterpret_cast<u32x4*>(dst + sb + mi * 32 + hi * 8) = s0;
    *reinterpret_cast<u32x4*>(dst + sb + mi * 32 + 16 + hi * 8) = s1;
  }
}

// ------ GEMM1 (triangular): S-tile once, store P[q,kv] and P[kv,q], Lp -----
// (verbatim from R11 — passing)
__launch_bounds__(512, 4)
__global__ void gemm1_kern(const f16* __restrict__ xh, const float* __restrict__ n2,
                           f16* __restrict__ P, float* __restrict__ Lp,
                           int b0, int bm, int bsh) {
  __shared__ __align__(16) char smem[65536];
  f16* Aq = (f16*)smem;            // 2 bufs x [128 q][64 d]
  f16* Bk = (f16*)(smem + 32768);  // 2 bufs x [128 kv][64 d]
  const int idx = blockIdx.x;
  const int bl = idx & bm;
  int tdec = idx >> bsh;           // 0..135
  int qt = 0;
#pragma unroll 1
  while (tdec >= 16 - qt) { tdec -= 16 - qt; ++qt; }
  const int kt = qt + tdec;
  const int b = b0 + bl;
  const int qb = qt * 128, kb = kt * 128;
  const int tid = threadIdx.x, lane = tid & 63, w = tid >> 6;
  const int l31 = lane & 31, hi = lane >> 5;
  const int wq = w >> 2, wk = w & 3;
  const f16* xb = xh + (size_t)b * S_ * D_;

#define G1_STAGE(st, pp)                                                       \
  { _Pragma("unroll") for (int i = 0; i < 4; ++i) {                            \
      int ii = w * 4 + i;                                                      \
      int flat = ii * 64 + lane;                                               \
      bool isB = ii >= 16;                                                     \
      int ch = isB ? flat - 1024 : flat;                                       \
      int r = ch >> 3, c = ch & 7;                                             \
      int csrc = c ^ (r & 7);                                                  \
      const f16* src = xb + (size_t)((isB ? kb : qb) + r) * 256 +              \
                       (st) * 64 + csrc * 8;                                   \
      f16* dst = (isB ? Bk : Aq) + ((pp) * 8192) + ch * 8;                     \
      gload_lds16(src, dst);                                                   \
    } }

  f32x16 acc[2];
#pragma unroll
  for (int i = 0; i < 2; ++i)
#pragma unroll
    for (int e = 0; e < 16; ++e) acc[i][e] = 0.0f;

  G1_STAGE(0, 0);
  __syncthreads();
#pragma unroll
  for (int t = 0; t < 4; ++t) {
    const int p = t & 1;
    if (t < 3) G1_STAGE(t + 1, p ^ 1);
#pragma unroll
    for (int kc = 0; kc < 4; ++kc) {
      int cc = ((2 * kc + hi) ^ (l31 & 7)) * 8;
      f16x8 af  = *reinterpret_cast<const f16x8*>(Bk + p * 8192 + (wk * 32 + l31) * 64 + cc);
      f16x8 bf0 = *reinterpret_cast<const f16x8*>(Aq + p * 8192 + (wq * 64 + l31) * 64 + cc);
      f16x8 bf1 = *reinterpret_cast<const f16x8*>(Aq + p * 8192 + (wq * 64 + 32 + l31) * 64 + cc);
      acc[0] = __builtin_amdgcn_mfma_f32_32x32x16_f16(af, bf0, acc[0], 0, 0, 0);
      acc[1] = __builtin_amdgcn_mfma_f32_32x32x16_f16(af, bf1, acc[1], 0, 0, 0);
    }
    __syncthreads();
  }
#undef G1_STAGE

  float* raw = (float*)smem;   // [128 kv][128 q]
  if (kt != qt) {
#pragma unroll
    for (int ni = 0; ni < 2; ++ni)
#pragma unroll
      for (int j = 0; j < 16; ++j) {
        int kvloc = wk * 32 + (j & 3) + 8 * (j >> 2) + 4 * hi;
        int qloc = wq * 64 + ni * 32 + l31;
        raw[kvloc * 128 + (qloc ^ ((kvloc & 7) << 2))] = acc[ni][j];
      }
  }

  float r2[2], lsum[2];
  int qrow[2];
#pragma unroll
  for (int ni = 0; ni < 2; ++ni) {
    qrow[ni] = qb + wq * 64 + ni * 32 + l31;
    r2[ni] = sqrtf(n2[b * S_ + qrow[ni]]) * (NMAXR * SC2F);
    lsum[ni] = 0.0f;
  }
#pragma unroll
  for (int ni = 0; ni < 2; ++ni)
#pragma unroll
    for (int j = 0; j < 16; ++j) {
      float v = exp2f(acc[ni][j] * SC2F - r2[ni]);
      acc[ni][j] = v;
      lsum[ni] += v;
    }
#pragma unroll
  for (int ni = 0; ni < 2; ++ni) lsum[ni] += __shfl_xor(lsum[ni], 32);

  const int colb = kb + wk * 32;
#pragma unroll
  for (int ni = 0; ni < 2; ++ni) {
    u32x4 s0, s1;
    pack16(acc[ni], hi, s0, s1);
    size_t rowp = (size_t)(bl * S_ + qrow[ni]) * 2048;
    *reinterpret_cast<u32x4*>(P + rowp + colb + hi * 8) = s0;
    *reinterpret_cast<u32x4*>(P + rowp + colb + 16 + hi * 8) = s1;
  }

  if (kt != qt) {
    __syncthreads();
    const int kvr = tid >> 2;
    const int qseg = (tid & 3) * 32;
    float r2kv = sqrtf(n2[b * S_ + kb + kvr]) * (NMAXR * SC2F);
    u32 ow[16];
    float tsum = 0.0f;
#pragma unroll
    for (int c8 = 0; c8 < 8; ++c8) {
      int qs = qseg + c8 * 4;
      float4 v = *reinterpret_cast<const float4*>(
          &raw[kvr * 128 + (qs ^ ((kvr & 7) << 2))]);
      float e0 = exp2f(v.x * SC2F - r2kv), e1 = exp2f(v.y * SC2F - r2kv);
      float e2 = exp2f(v.z * SC2F - r2kv), e3 = exp2f(v.w * SC2F - r2kv);
      tsum += (e0 + e1) + (e2 + e3);
      ow[c8 * 2 + 0] = packf16(e0, e1);
      ow[c8 * 2 + 1] = packf16(e2, e3);
    }
    size_t rowp = (size_t)(bl * S_ + kb + kvr) * 2048;
#pragma unroll
    for (int sseg = 0; sseg < 4; ++sseg) {
      u32x4 sv;
      sv[0] = ow[sseg * 4 + 0]; sv[1] = ow[sseg * 4 + 1];
      sv[2] = ow[sseg * 4 + 2]; sv[3] = ow[sseg * 4 + 3];
      *reinterpret_cast<u32x4*>(P + rowp + qb + qseg + sseg * 8) = sv;
    }
    tsum += __shfl_xor(tsum, 1);
    tsum += __shfl_xor(tsum, 2);
    if ((tid & 3) == 0)
      Lp[(size_t)(bl * 16 + qt) * 2048 + kb + kvr] = tsum;
  }

  __syncthreads();
  float* Lred = (float*)smem;   // [128 q][4 wk]
  if (hi == 0) {
    Lred[(wq * 64 + l31) * 4 + wk] = lsum[0];
    Lred[(wq * 64 + 32 + l31) * 4 + wk] = lsum[1];
  }
  __syncthreads();
  if (tid < 128) {
    float s = Lred[tid * 4] + Lred[tid * 4 + 1] + Lred[tid * 4 + 2] + Lred[tid * 4 + 3];
    Lp[(size_t)(bl * 16 + kt) * 2048 + qb + tid] = s;
  }
}

// ------ GEMM2P: out = reparam( (P @ XWt^T)/L + bias ) ----------------------
// tile 64q x 128j, K=2048 in 32 steps of 64; grid bpp*32 (b fastest)
// 4 waves (wq2 x wc2): wave 32q x paired cols {wc*32.., 64+wc*32..}, acc[2]
__launch_bounds__(256, 3)
__global__ void gemm2p_kern(const f16* __restrict__ P, const f16* __restrict__ XWt,
                            const float* __restrict__ Lp, const float* __restrict__ bm,
                            const float* __restrict__ bl_, const float* __restrict__ eps,
                            float* __restrict__ out, int b0, int bm_, int bsh) {
  __shared__ f16 Pq[2][4096];   // [buf][64 q][64 kv]
  __shared__ f16 Xw[2][8192];   // [buf][128 j][64 kv]
  const int idx = blockIdx.x;
  const int bl = idx & bm_;
  const int qt = idx >> bsh;    // 0..31
  const int b = b0 + bl;
  const int qb = qt * 64;
  const int tid = threadIdx.x, lane = tid & 63, w = tid >> 6;
  const int l31 = lane & 31, hi = lane >> 5;
  const int wq = w & 1, wc = w >> 1;
  const f16* xwb = XWt + (size_t)b * 128 * 2048;

#define GP_STAGE(tt, pp)                                                       \
  {                                                                            \
    _Pragma("unroll") for (int i = 0; i < 2; ++i) {                            \
      int ch = i * 256 + tid; int r = ch >> 3, c = ch & 7;                     \
      int csrc = c ^ (r & 7);                                                  \
      gload_lds16(P + (size_t)(bl * S_ + qb + r) * 2048 + ((tt) * 64) + csrc * 8, \
                  &Pq[(pp)][0] + ch * 8);                                      \
    }                                                                          \
    _Pragma("unroll") for (int i = 0; i < 4; ++i) {                            \
      int ch = i * 256 + tid; int r = ch >> 3, c = ch & 7;                     \
      int csrc = c ^ (r & 7);                                                  \
      gload_lds16(xwb + (size_t)r * 2048 + ((tt) * 64) + csrc * 8,             \
                  &Xw[(pp)][0] + ch * 8);                                      \
    }                                                                          \
  }

  f32x16 acc[2];
#pragma unroll
  for (int i = 0; i < 2; ++i)
#pragma unroll
    for (int e = 0; e < 16; ++e) acc[i][e] = 0.0f;

  GP_STAGE(0, 0);
  __syncthreads();
#pragma unroll 1
  for (int t = 0; t < 32; ++t) {
    const int p = t & 1;
    if (t < 31) GP_STAGE(t + 1, p ^ 1);
#pragma unroll
    for (int kc = 0; kc < 4; ++kc) {
      int cc = ((2 * kc + hi) ^ (l31 & 7)) * 8;
      f16x8 bf = *reinterpret_cast<const f16x8*>(&Pq[p][(wq * 32 + l31) * 64 + cc]);
#pragma unroll
      for (int mi = 0; mi < 2; ++mi) {
        int jrow = mi * 64 + wc * 32 + l31;
        f16x8 af = *reinterpret_cast<const f16x8*>(&Xw[p][jrow * 64 + cc]);
        acc[mi] = __builtin_amdgcn_mfma_f32_32x32x16_f16(af, bf, acc[mi], 0, 0, 0);
      }
    }
    __syncthreads();
  }
#undef GP_STAGE

  // epilogue: acc[0] = mean-raw (cols wc*32..), acc[1] = logvar-raw (+64)
  const int q = qb + wq * 32 + l31;
  const int grow = b * S_ + q;
  float L = 0.0f;
#pragma unroll
  for (int kt = 0; kt < 16; ++kt) L += Lp[(size_t)(bl * 16 + kt) * 2048 + q];
  float rL = 1.0f / L;
#pragma unroll
  for (int jg = 0; jg < 4; ++jg) {
    int cb = wc * 32 + 8 * jg + 4 * hi;
    float4 bmv = *reinterpret_cast<const float4*>(bm + cb);
    float4 blv = *reinterpret_cast<const float4*>(bl_ + cb);
    float4 ev  = *reinterpret_cast<const float4*>(eps + (size_t)grow * 64 + cb);
    float4 mn, lv, av;
    float* mnp = &mn.x; float* lvp = &lv.x; float* avp = &av.x;
    const float* bmp = &bmv.x; const float* blp = &blv.x; const float* evp = &ev.x;
#pragma unroll
    for (int jj = 0; jj < 4; ++jj) {
      int j = jg * 4 + jj;
      float m = acc[0][j] * rL + bmp[jj];
      float l = acc[1][j] * rL + blp[jj];
      mnp[jj] = m;
      lvp[jj] = l;
      avp[jj] = m + exp2f(0.7213475204f * l) * evp[jj];
    }
    float* o0 = out + (size_t)grow * 64 + cb;
    *reinterpret_cast<float4*>(o0) = mn;
    *reinterpret_cast<float4*>(o0 + 1048576) = lv;
    *reinterpret_cast<float4*>(o0 + 2097152) = av;
  }
}

extern "C" void kernel_launch(void* const* d_in, const int* in_sizes, int n_in,
                              void* d_out, int out_size, void* d_ws, size_t ws_size,
                              hipStream_t stream) {
  (void)in_sizes; (void)n_in; (void)out_size;
  const float* x   = (const float*)d_in[0];
  const float* Wm  = (const float*)d_in[1];
  const float* bmv = (const float*)d_in[2];
  const float* Wl  = (const float*)d_in[3];
  const float* blv = (const float*)d_in[4];
  const float* ep  = (const float*)d_in[5];
  float* out = (float*)d_out;

  char* ws = (char*)d_ws;
  f16*   xh   = (f16*)(ws + 0);              //  8 MB
  f16*   XWt  = (f16*)(ws + 8388608);        //  4 MB
  f16*   Wt   = (f16*)(ws + 12582912);       // 64 KB
  float* n2   = (float*)(ws + 12648448);     // 64 KB
  float* Lp   = (float*)(ws + 12713984);     // <=1 MB
  const size_t P_off = 13762560;
  f16*   Pbuf = (f16*)(ws + P_off);

  int bpp = 1;
  if      (ws_size >= P_off + (size_t)8 * 2048 * 2048 * 2) bpp = 8;
  else if (ws_size >= P_off + (size_t)4 * 2048 * 2048 * 2) bpp = 4;
  else if (ws_size >= P_off + (size_t)2 * 2048 * 2048 * 2) bpp = 2;
  const int bsh = (bpp == 8) ? 3 : (bpp == 4) ? 2 : (bpp == 2) ? 1 : 0;
  const int bm = bpp - 1;

  prep<<<288, 256, 0, stream>>>(x, Wm, Wl, xh, n2, Wt);
  xw_kern<<<256, 256, 0, stream>>>(xh, Wt, XWt);
  for (int b0 = 0; b0 < 8; b0 += bpp) {
    gemm1_kern<<<bpp * 136, 512, 0, stream>>>(xh, n2, Pbuf, Lp, b0, bm, bsh);
    gemm2p_kern<<<bpp * 32, 256, 0, stream>>>(Pbuf, XWt, Lp, bmv, blv, ep, out,
                                              b0, bm, bsh);
  }
  proj_dummy:;
}

// Round 13
// 74.175 us; speedup vs baseline: 1.2108x; 1.0233x over previous
//
#include <hip/hip_runtime.h>

#define B_ 8
#define S_ 2048
#define D_ 256

typedef _Float16 f16;
typedef f16 f16x2 __attribute__((ext_vector_type(2)));
typedef f16 f16x8 __attribute__((ext_vector_type(8)));
typedef float f32x16 __attribute__((ext_vector_type(16)));
typedef unsigned int u32;
typedef u32 u32x4 __attribute__((ext_vector_type(4)));

typedef const __attribute__((address_space(1))) unsigned int* gptr_t;
typedef __attribute__((address_space(3))) unsigned int* lptr_t;

__device__ __forceinline__ void gload_lds16(const void* g, void* l) {
  __builtin_amdgcn_global_load_lds((gptr_t)(unsigned long long)g,
                                   (lptr_t)(unsigned long long)l, 16, 0, 0);
}

__device__ __forceinline__ u32 packf16(float a, float b) {
  f16x2 t; t[0] = (f16)a; t[1] = (f16)b;
  return __builtin_bit_cast(u32, t);
}

// acc (lane-dim col, crow rows) -> lane holds its lane-row, crow-contiguous:
// s0 = crow 0..15 (16B at +hi*8), s1 = crow 16..31 (+16+hi*8).
__device__ __forceinline__ void pack16(const f32x16& p, int hi, u32x4& o0, u32x4& o1) {
#pragma unroll
  for (int c2 = 0; c2 < 2; ++c2) {
    u32 a1 = packf16(p[8 * c2 + 0], p[8 * c2 + 1]);
    u32 a2 = packf16(p[8 * c2 + 2], p[8 * c2 + 3]);
    u32 b1 = packf16(p[8 * c2 + 4], p[8 * c2 + 5]);
    u32 b2 = packf16(p[8 * c2 + 6], p[8 * c2 + 7]);
    u32 xa1 = __shfl_xor(a1, 32), xa2 = __shfl_xor(a2, 32);
    u32 xb1 = __shfl_xor(b1, 32), xb2 = __shfl_xor(b2, 32);
    u32x4 f;
    f[0] = hi ? xb1 : a1;
    f[1] = hi ? xb2 : a2;
    f[2] = hi ? b1 : xa1;
    f[3] = hi ? b2 : xa2;
    if (c2) o1 = f; else o0 = f;
  }
}

#define SC2F 0.09016844f   // log2(e)/16
#define NMAXR 20.0f        // >= max row norm (chi2_256 max ~ sqrt(397))

// ---- fused prep: xh (f16), n2 (row norms^2), Wt[128 j][256 d] -------------
__global__ void prep(const float* __restrict__ x, const float* __restrict__ Wm,
                     const float* __restrict__ Wl, f16* __restrict__ xh,
                     float* __restrict__ n2, f16* __restrict__ Wt) {
  __shared__ f16 tile[64][264];
  const int bid = blockIdx.x;
  const int t = threadIdx.x;          // 256
  if (bid < 256) {
    const int b = bid >> 5, st = bid & 31;
    const int s0 = st * 64;
    const float* xb = x + ((size_t)(b * S_ + s0)) * D_;
    f16* xhb = xh + ((size_t)(b * S_ + s0)) * D_;
#pragma unroll
    for (int it = 0; it < 16; ++it) {
      int flat = it * 256 + t;
      int r = flat >> 6, c4 = flat & 63;
      float4 v = *reinterpret_cast<const float4*>(xb + r * 256 + c4 * 4);
      f16 h0 = (f16)v.x, h1 = (f16)v.y, h2 = (f16)v.z, h3 = (f16)v.w;
      f16x2 p0 = {h0, h1}, p1 = {h2, h3};
      uint2 wv; wv.x = __builtin_bit_cast(u32, p0); wv.y = __builtin_bit_cast(u32, p1);
      *reinterpret_cast<uint2*>(xhb + r * 256 + c4 * 4) = wv;
      tile[r][c4 * 4 + 0] = h0; tile[r][c4 * 4 + 1] = h1;
      tile[r][c4 * 4 + 2] = h2; tile[r][c4 * 4 + 3] = h3;
    }
    __syncthreads();
    {
      int r = t >> 2, qd = t & 3;
      float s = 0.0f;
#pragma unroll
      for (int i = 0; i < 8; ++i) {
        f16x8 v = *reinterpret_cast<const f16x8*>(&tile[r][qd * 64 + i * 8]);
#pragma unroll
        for (int u = 0; u < 8; ++u) { float f = (float)v[u]; s += f * f; }
      }
      s += __shfl_xor(s, 1); s += __shfl_xor(s, 2);
      if (qd == 0) n2[b * S_ + s0 + r] = s;
    }
  } else {
    int idx = (bid - 256) * 1024 + t * 4;
    int j = idx >> 8, d = idx & 255;
#pragma unroll
    for (int k2 = 0; k2 < 4; ++k2) {
      float v = (j < 64) ? Wm[(d + k2) * 64 + j] : Wl[(d + k2) * 64 + (j - 64)];
      Wt[idx + k2] = (f16)v;
    }
  }
}

// ---- xw: XWt[b][j 128][s 2048] = (xh @ Wt^T)^T, f16 -----------------------
__launch_bounds__(256)
__global__ void xw_kern(const f16* __restrict__ xh, const f16* __restrict__ Wt,
                        f16* __restrict__ XWt) {
  __shared__ f16 Ax[2][4096];   // [buf][64 s][64 d]
  __shared__ f16 Ww[2][8192];   // [buf][128 j][64 d]
  const int idx = blockIdx.x;
  const int b = idx & 7;
  const int sb = (idx >> 3) * 64;
  const int tid = threadIdx.x, lane = tid & 63, w = tid >> 6;   // w = wj
  const int l31 = lane & 31, hi = lane >> 5;
  const f16* xb = xh + (size_t)b * S_ * D_;

#define XW_STAGE(st, pp)                                                       \
  {                                                                            \
    _Pragma("unroll") for (int i = 0; i < 2; ++i) {                            \
      int ch = i * 256 + tid; int r = ch >> 3, c = ch & 7;                     \
      int csrc = c ^ (r & 7);                                                  \
      gload_lds16(xb + (size_t)(sb + r) * 256 + ((st) * 64) + csrc * 8,        \
                  &Ax[(pp)][0] + ch * 8);                                      \
    }                                                                          \
    _Pragma("unroll") for (int i = 0; i < 4; ++i) {                            \
      int ch = i * 256 + tid; int r = ch >> 3, c = ch & 7;                     \
      int csrc = c ^ (r & 7);                                                  \
      gload_lds16(Wt + (size_t)r * 256 + ((st) * 64) + csrc * 8,               \
                  &Ww[(pp)][0] + ch * 8);                                      \
    }                                                                          \
  }

  f32x16 acc[2];
#pragma unroll
  for (int i = 0; i < 2; ++i)
#pragma unroll
    for (int e = 0; e < 16; ++e) acc[i][e] = 0.0f;

  XW_STAGE(0, 0);
  __syncthreads();
#pragma unroll
  for (int t = 0; t < 4; ++t) {
    const int p = t & 1;
    if (t < 3) XW_STAGE(t + 1, p ^ 1);
#pragma unroll
    for (int kc = 0; kc < 4; ++kc) {
      int cc = ((2 * kc + hi) ^ (l31 & 7)) * 8;
      f16x8 bf = *reinterpret_cast<const f16x8*>(&Ww[p][(w * 32 + l31) * 64 + cc]);
#pragma unroll
      for (int mi = 0; mi < 2; ++mi) {
        f16x8 af = *reinterpret_cast<const f16x8*>(&Ax[p][(mi * 32 + l31) * 64 + cc]);
        acc[mi] = __builtin_amdgcn_mfma_f32_32x32x16_f16(af, bf, acc[mi], 0, 0, 0);
      }
    }
    __syncthreads();
  }
#undef XW_STAGE

  const int j = w * 32 + l31;
  f16* dst = XWt + ((size_t)b * 128 + j) * 2048;
#pragma unroll
  for (int mi = 0; mi < 2; ++mi) {
    u32x4 s0, s1;
    pack16(acc[mi], hi, s0, s1);
    *reinterpret_cast<u32x4*>(dst + sb + mi * 32 + hi * 8) = s0;
    *reinterpret_cast<u32x4*>(dst + sb + mi * 32 + 16 + hi * 8) = s1;
  }
}

// ------ GEMM1 (triangular): S-tile once, store P[q,kv] and P[kv,q], Lp -----
// (verbatim from R11 — passing)
__launch_bounds__(512, 4)
__global__ void gemm1_kern(const f16* __restrict__ xh, const float* __restrict__ n2,
                           f16* __restrict__ P, float* __restrict__ Lp,
                           int b0, int bm, int bsh) {
  __shared__ __align__(16) char smem[65536];
  f16* Aq = (f16*)smem;            // 2 bufs x [128 q][64 d]
  f16* Bk = (f16*)(smem + 32768);  // 2 bufs x [128 kv][64 d]
  const int idx = blockIdx.x;
  const int bl = idx & bm;
  int tdec = idx >> bsh;           // 0..135
  int qt = 0;
#pragma unroll 1
  while (tdec >= 16 - qt) { tdec -= 16 - qt; ++qt; }
  const int kt = qt + tdec;
  const int b = b0 + bl;
  const int qb = qt * 128, kb = kt * 128;
  const int tid = threadIdx.x, lane = tid & 63, w = tid >> 6;
  const int l31 = lane & 31, hi = lane >> 5;
  const int wq = w >> 2, wk = w & 3;
  const f16* xb = xh + (size_t)b * S_ * D_;

#define G1_STAGE(st, pp)                                                       \
  { _Pragma("unroll") for (int i = 0; i < 4; ++i) {                            \
      int ii = w * 4 + i;                                                      \
      int flat = ii * 64 + lane;                                               \
      bool isB = ii >= 16;                                                     \
      int ch = isB ? flat - 1024 : flat;                                       \
      int r = ch >> 3, c = ch & 7;                                             \
      int csrc = c ^ (r & 7);                                                  \
      const f16* src = xb + (size_t)((isB ? kb : qb) + r) * 256 +              \
                       (st) * 64 + csrc * 8;                                   \
      f16* dst = (isB ? Bk : Aq) + ((pp) * 8192) + ch * 8;                     \
      gload_lds16(src, dst);                                                   \
    } }

  f32x16 acc[2];
#pragma unroll
  for (int i = 0; i < 2; ++i)
#pragma unroll
    for (int e = 0; e < 16; ++e) acc[i][e] = 0.0f;

  G1_STAGE(0, 0);
  __syncthreads();
#pragma unroll
  for (int t = 0; t < 4; ++t) {
    const int p = t & 1;
    if (t < 3) G1_STAGE(t + 1, p ^ 1);
#pragma unroll
    for (int kc = 0; kc < 4; ++kc) {
      int cc = ((2 * kc + hi) ^ (l31 & 7)) * 8;
      f16x8 af  = *reinterpret_cast<const f16x8*>(Bk + p * 8192 + (wk * 32 + l31) * 64 + cc);
      f16x8 bf0 = *reinterpret_cast<const f16x8*>(Aq + p * 8192 + (wq * 64 + l31) * 64 + cc);
      f16x8 bf1 = *reinterpret_cast<const f16x8*>(Aq + p * 8192 + (wq * 64 + 32 + l31) * 64 + cc);
      acc[0] = __builtin_amdgcn_mfma_f32_32x32x16_f16(af, bf0, acc[0], 0, 0, 0);
      acc[1] = __builtin_amdgcn_mfma_f32_32x32x16_f16(af, bf1, acc[1], 0, 0, 0);
    }
    __syncthreads();
  }
#undef G1_STAGE

  float* raw = (float*)smem;   // [128 kv][128 q]
  if (kt != qt) {
#pragma unroll
    for (int ni = 0; ni < 2; ++ni)
#pragma unroll
      for (int j = 0; j < 16; ++j) {
        int kvloc = wk * 32 + (j & 3) + 8 * (j >> 2) + 4 * hi;
        int qloc = wq * 64 + ni * 32 + l31;
        raw[kvloc * 128 + (qloc ^ ((kvloc & 7) << 2))] = acc[ni][j];
      }
  }

  float r2[2], lsum[2];
  int qrow[2];
#pragma unroll
  for (int ni = 0; ni < 2; ++ni) {
    qrow[ni] = qb + wq * 64 + ni * 32 + l31;
    r2[ni] = sqrtf(n2[b * S_ + qrow[ni]]) * (NMAXR * SC2F);
    lsum[ni] = 0.0f;
  }
#pragma unroll
  for (int ni = 0; ni < 2; ++ni)
#pragma unroll
    for (int j = 0; j < 16; ++j) {
      float v = exp2f(acc[ni][j] * SC2F - r2[ni]);
      acc[ni][j] = v;
      lsum[ni] += v;
    }
#pragma unroll
  for (int ni = 0; ni < 2; ++ni) lsum[ni] += __shfl_xor(lsum[ni], 32);

  const int colb = kb + wk * 32;
#pragma unroll
  for (int ni = 0; ni < 2; ++ni) {
    u32x4 s0, s1;
    pack16(acc[ni], hi, s0, s1);
    size_t rowp = (size_t)(bl * S_ + qrow[ni]) * 2048;
    *reinterpret_cast<u32x4*>(P + rowp + colb + hi * 8) = s0;
    *reinterpret_cast<u32x4*>(P + rowp + colb + 16 + hi * 8) = s1;
  }

  if (kt != qt) {
    __syncthreads();
    const int kvr = tid >> 2;
    const int qseg = (tid & 3) * 32;
    float r2kv = sqrtf(n2[b * S_ + kb + kvr]) * (NMAXR * SC2F);
    u32 ow[16];
    float tsum = 0.0f;
#pragma unroll
    for (int c8 = 0; c8 < 8; ++c8) {
      int qs = qseg + c8 * 4;
      float4 v = *reinterpret_cast<const float4*>(
          &raw[kvr * 128 + (qs ^ ((kvr & 7) << 2))]);
      float e0 = exp2f(v.x * SC2F - r2kv), e1 = exp2f(v.y * SC2F - r2kv);
      float e2 = exp2f(v.z * SC2F - r2kv), e3 = exp2f(v.w * SC2F - r2kv);
      tsum += (e0 + e1) + (e2 + e3);
      ow[c8 * 2 + 0] = packf16(e0, e1);
      ow[c8 * 2 + 1] = packf16(e2, e3);
    }
    size_t rowp = (size_t)(bl * S_ + kb + kvr) * 2048;
#pragma unroll
    for (int sseg = 0; sseg < 4; ++sseg) {
      u32x4 sv;
      sv[0] = ow[sseg * 4 + 0]; sv[1] = ow[sseg * 4 + 1];
      sv[2] = ow[sseg * 4 + 2]; sv[3] = ow[sseg * 4 + 3];
      *reinterpret_cast<u32x4*>(P + rowp + qb + qseg + sseg * 8) = sv;
    }
    tsum += __shfl_xor(tsum, 1);
    tsum += __shfl_xor(tsum, 2);
    if ((tid & 3) == 0)
      Lp[(size_t)(bl * 16 + qt) * 2048 + kb + kvr] = tsum;
  }

  __syncthreads();
  float* Lred = (float*)smem;   // [128 q][4 wk]
  if (hi == 0) {
    Lred[(wq * 64 + l31) * 4 + wk] = lsum[0];
    Lred[(wq * 64 + 32 + l31) * 4 + wk] = lsum[1];
  }
  __syncthreads();
  if (tid < 128) {
    float s = Lred[tid * 4] + Lred[tid * 4 + 1] + Lred[tid * 4 + 2] + Lred[tid * 4 + 3];
    Lp[(size_t)(bl * 16 + kt) * 2048 + qb + tid] = s;
  }
}

// ------ GEMM2P (split-K=2): Yp[ks] = (P @ XWt^T)/L over K-half -------------
// tile 64q x 128j, K-half=1024 in 16 steps of 64; grid bpp*64:
//   bl = idx & (bpp-1), qt = next 5 bits, ks = top bit
// 4 waves (wq2 x wc2): wave 32q x paired cols {wc*32, 64+wc*32}, acc[2]
__launch_bounds__(256, 3)
__global__ void gemm2p_kern(const f16* __restrict__ P, const f16* __restrict__ XWt,
                            const float* __restrict__ Lp, float* __restrict__ Yp,
                            int b0, int bm_, int bsh, int kso) {
  __shared__ f16 Pq[2][4096];   // [buf][64 q][64 kv]
  __shared__ f16 Xw[2][8192];   // [buf][128 j][64 kv]
  const int idx = blockIdx.x;
  const int bl = idx & bm_;
  const int qt = (idx >> bsh) & 31;
  const int ks = idx >> (bsh + 5);   // 0 or 1
  const int b = b0 + bl;
  const int qb = qt * 64;
  const int kcol0 = ks * 1024;
  const int tid = threadIdx.x, lane = tid & 63, w = tid >> 6;
  const int l31 = lane & 31, hi = lane >> 5;
  const int wq = w & 1, wc = w >> 1;
  const f16* xwb = XWt + (size_t)b * 128 * 2048;

#define GP_STAGE(tt, pp)                                                       \
  {                                                                            \
    _Pragma("unroll") for (int i = 0; i < 2; ++i) {                            \
      int ch = i * 256 + tid; int r = ch >> 3, c = ch & 7;                     \
      int csrc = c ^ (r & 7);                                                  \
      gload_lds16(P + (size_t)(bl * S_ + qb + r) * 2048 + kcol0 + ((tt) * 64) + csrc * 8, \
                  &Pq[(pp)][0] + ch * 8);                                      \
    }                                                                          \
    _Pragma("unroll") for (int i = 0; i < 4; ++i) {                            \
      int ch = i * 256 + tid; int r = ch >> 3, c = ch & 7;                     \
      int csrc = c ^ (r & 7);                                                  \
      gload_lds16(xwb + (size_t)r * 2048 + kcol0 + ((tt) * 64) + csrc * 8,     \
                  &Xw[(pp)][0] + ch * 8);                                      \
    }                                                                          \
  }

  f32x16 acc[2];
#pragma unroll
  for (int i = 0; i < 2; ++i)
#pragma unroll
    for (int e = 0; e < 16; ++e) acc[i][e] = 0.0f;

  GP_STAGE(0, 0);
  __syncthreads();
#pragma unroll 1
  for (int t = 0; t < 16; ++t) {
    const int p = t & 1;
    if (t < 15) GP_STAGE(t + 1, p ^ 1);
#pragma unroll
    for (int kc = 0; kc < 4; ++kc) {
      int cc = ((2 * kc + hi) ^ (l31 & 7)) * 8;
      f16x8 bf = *reinterpret_cast<const f16x8*>(&Pq[p][(wq * 32 + l31) * 64 + cc]);
#pragma unroll
      for (int mi = 0; mi < 2; ++mi) {
        int jrow = mi * 64 + wc * 32 + l31;
        f16x8 af = *reinterpret_cast<const f16x8*>(&Xw[p][jrow * 64 + cc]);
        acc[mi] = __builtin_amdgcn_mfma_f32_32x32x16_f16(af, bf, acc[mi], 0, 0, 0);
      }
    }
    __syncthreads();
  }
#undef GP_STAGE

  // epilogue: apply rL to partials, store f32
  const int q = qb + wq * 32 + l31;
  float L = 0.0f;
#pragma unroll
  for (int kt = 0; kt < 16; ++kt) L += Lp[(size_t)(bl * 16 + kt) * 2048 + q];
  float rL = 1.0f / L;
  float* dst = Yp + ((size_t)ks * kso + (size_t)bl * 2048 + q) * 128;
#pragma unroll
  for (int jg = 0; jg < 4; ++jg) {
    int cb = wc * 32 + 8 * jg + 4 * hi;
    float4 mn, lv;
    float* mnp = &mn.x; float* lvp = &lv.x;
#pragma unroll
    for (int jj = 0; jj < 4; ++jj) {
      int j = jg * 4 + jj;
      mnp[jj] = acc[0][j] * rL;
      lvp[jj] = acc[1][j] * rL;
    }
    *reinterpret_cast<float4*>(dst + cb) = mn;
    *reinterpret_cast<float4*>(dst + 64 + cb) = lv;
  }
}

// ------ reduce: out = reparam( Yp0 + Yp1 + bias ) --------------------------
// grid bpp*64: block = 32 rows x 64 paired cols; thread = 1 row x 8 cols
__launch_bounds__(256)
__global__ void reduce_kern(const float* __restrict__ Yp, const float* __restrict__ bm,
                            const float* __restrict__ bl_, const float* __restrict__ eps,
                            float* __restrict__ out, int b0, int kso) {
  const int t = threadIdx.x;
  const int rowp = blockIdx.x * 32 + (t >> 3);
  const int j0 = (t & 7) * 8;
  const int grow = b0 * 2048 + rowp;
  const float* y0 = Yp + (size_t)rowp * 128;
  const float* y1 = Yp + (size_t)kso * 128 + (size_t)rowp * 128;
  float mv[8], lv[8], ev[8];
#pragma unroll
  for (int i = 0; i < 2; ++i) {
    float4 a = *reinterpret_cast<const float4*>(y0 + j0 + i * 4);
    float4 b = *reinterpret_cast<const float4*>(y1 + j0 + i * 4);
    float4 c = *reinterpret_cast<const float4*>(y0 + 64 + j0 + i * 4);
    float4 d = *reinterpret_cast<const float4*>(y1 + 64 + j0 + i * 4);
    float4 e = *reinterpret_cast<const float4*>(eps + (size_t)grow * 64 + j0 + i * 4);
    mv[i*4+0] = a.x + b.x; mv[i*4+1] = a.y + b.y; mv[i*4+2] = a.z + b.z; mv[i*4+3] = a.w + b.w;
    lv[i*4+0] = c.x + d.x; lv[i*4+1] = c.y + d.y; lv[i*4+2] = c.z + d.z; lv[i*4+3] = c.w + d.w;
    ev[i*4+0] = e.x; ev[i*4+1] = e.y; ev[i*4+2] = e.z; ev[i*4+3] = e.w;
  }
  float om[8], ol[8], oa[8];
#pragma unroll
  for (int i = 0; i < 8; ++i) {
    float m = mv[i] + bm[j0 + i];
    float l = lv[i] + bl_[j0 + i];
    om[i] = m;
    ol[i] = l;
    oa[i] = m + exp2f(0.7213475204f * l) * ev[i];
  }
  float* o0 = out + (size_t)grow * 64 + j0;
#pragma unroll
  for (int i = 0; i < 2; ++i) {
    *reinterpret_cast<float4*>(o0 + i * 4) = *reinterpret_cast<float4*>(&om[i * 4]);
    *reinterpret_cast<float4*>(o0 + 1048576 + i * 4) = *reinterpret_cast<float4*>(&ol[i * 4]);
    *reinterpret_cast<float4*>(o0 + 2097152 + i * 4) = *reinterpret_cast<float4*>(&oa[i * 4]);
  }
}

extern "C" void kernel_launch(void* const* d_in, const int* in_sizes, int n_in,
                              void* d_out, int out_size, void* d_ws, size_t ws_size,
                              hipStream_t stream) {
  (void)in_sizes; (void)n_in; (void)out_size;
  const float* x   = (const float*)d_in[0];
  const float* Wm  = (const float*)d_in[1];
  const float* bmv = (const float*)d_in[2];
  const float* Wl  = (const float*)d_in[3];
  const float* blv = (const float*)d_in[4];
  const float* ep  = (const float*)d_in[5];
  float* out = (float*)d_out;

  char* ws = (char*)d_ws;
  f16*   xh   = (f16*)(ws + 0);              //  8 MB
  f16*   XWt  = (f16*)(ws + 8388608);        //  4 MB
  f16*   Wt   = (f16*)(ws + 12582912);       // 64 KB
  float* n2   = (float*)(ws + 12648448);     // 64 KB
  float* Lp   = (float*)(ws + 12713984);     // <=1 MB
  float* Yp   = (float*)(ws + 13762560);     // <=16 MB (split-K partials)
  const size_t P_off = 30539776;
  f16*   Pbuf = (f16*)(ws + P_off);

  int bpp = 1;
  if      (ws_size >= P_off + (size_t)8 * 2048 * 2048 * 2) bpp = 8;
  else if (ws_size >= P_off + (size_t)4 * 2048 * 2048 * 2) bpp = 4;
  else if (ws_size >= P_off + (size_t)2 * 2048 * 2048 * 2) bpp = 2;
  const int bsh = (bpp == 8) ? 3 : (bpp == 4) ? 2 : (bpp == 2) ? 1 : 0;
  const int bm = bpp - 1;
  const int kso = bpp * 2048;

  prep<<<288, 256, 0, stream>>>(x, Wm, Wl, xh, n2, Wt);
  xw_kern<<<256, 256, 0, stream>>>(xh, Wt, XWt);
  for (int b0 = 0; b0 < 8; b0 += bpp) {
    gemm1_kern<<<bpp * 136, 512, 0, stream>>>(xh, n2, Pbuf, Lp, b0, bm, bsh);
    gemm2p_kern<<<bpp * 64, 256, 0, stream>>>(Pbuf, XWt, Lp, Yp, b0, bm, bsh, kso);
    reduce_kern<<<bpp * 64, 256, 0, stream>>>(Yp, bmv, blv, ep, out, b0, kso);
  }
}